// Round 7
// baseline (403.883 us; speedup 1.0000x reference)
//
#include <hip/hip_runtime.h>
#include <math.h>

#define BB   16
#define LL   512
#define DD   512
#define HH   8
#define HDIM 64
#define NNEWT 12

typedef unsigned short ushort_t;
typedef __attribute__((ext_vector_type(8))) short short8;
typedef __attribute__((ext_vector_type(4))) float f32x4;

// raw single-instruction transcendentals
__device__ __forceinline__ float hw_log2(float x) { return __builtin_amdgcn_logf(x); }
__device__ __forceinline__ float hw_exp2(float x) { return __builtin_amdgcn_exp2f(x); }

__device__ __forceinline__ ushort_t f2b(float f) {
    unsigned u = __builtin_bit_cast(unsigned, f);
    unsigned r = u + 0x7FFFu + ((u >> 16) & 1u);     // RNE
    return (ushort_t)(r >> 16);
}

// ---------------- wave-wide reduction (64 lanes) for ln ----------------
__device__ __forceinline__ float wsum(float v) {
    v += __shfl_xor(v, 1);  v += __shfl_xor(v, 2);  v += __shfl_xor(v, 4);
    v += __shfl_xor(v, 8);  v += __shfl_xor(v, 16); v += __shfl_xor(v, 32);
    return v;
}

// ---------------- DPP 16-lane-group butterflies ----------------
template<int CTRL>
__device__ __forceinline__ float dpp_mov(float v) {
    return __builtin_bit_cast(float, __builtin_amdgcn_update_dpp(
        0, __builtin_bit_cast(int, v), CTRL, 0xf, 0xf, true));
}
__device__ __forceinline__ float rsum16(float v) {
    v += dpp_mov<0xB1>(v);
    v += dpp_mov<0x4E>(v);
    v += dpp_mov<0x141>(v);
    v += dpp_mov<0x140>(v);
    return v;
}
__device__ __forceinline__ float rmax16(float v) {
    v = fmaxf(v, dpp_mov<0xB1>(v));
    v = fmaxf(v, dpp_mov<0x4E>(v));
    v = fmaxf(v, dpp_mov<0x141>(v));
    v = fmaxf(v, dpp_mov<0x140>(v));
    return v;
}

// ---------------- fp32 -> bf16 conversion (memory-bound) ----------------
__global__ __launch_bounds__(256) void conv_f2b(const float* __restrict__ in,
                                                ushort_t* __restrict__ out)
{
    int i = (blockIdx.x * 256 + threadIdx.x) * 4;
    float4 v = *(const float4*)&in[i];
    ushort4 o;
    o.x = f2b(v.x); o.y = f2b(v.y); o.z = f2b(v.z); o.w = f2b(v.w);
    *(ushort4*)&out[i] = o;
}

// ---------------- bf16 MFMA GEMM: C = act(A @ W^T + bias) [+ resid] ----------------
__device__ __forceinline__ void gload16(const void* g, void* l) {
    __builtin_amdgcn_global_load_lds(
        (const __attribute__((address_space(1))) unsigned*)g,
        (__attribute__((address_space(3))) unsigned*)l, 16, 0, 0);
}

template<int ACT, bool RES, bool OBF16>
__global__ __launch_bounds__(256) void gemm_mfma(
    const ushort_t* __restrict__ A, const ushort_t* __restrict__ W,
    const float* __restrict__ bias, const float* __restrict__ resid,
    void* __restrict__ Cout, int M, int N, int K)
{
    __shared__ ushort_t Asw[64 * 64];
    __shared__ ushort_t Bsw[64 * 64];

    const int tid = threadIdx.x;
    const int w = tid >> 6, lane = tid & 63;
    const int wm = w >> 1, wn = w & 1;
    const int bm = blockIdx.y * 64, bn = blockIdx.x * 64;

    const int l3 = lane >> 3, l7 = lane & 7;
    const int srcg = l7 ^ l3;               // pre-swizzled source granule
    const int l15 = lane & 15, hi = lane >> 4;

    f32x4 acc[2][2] = {};

    for (int kt = 0; kt < K; kt += 64) {
        #pragma unroll
        for (int u = 0; u < 2; ++u) {
            int q = w * 2 + u;
            gload16(&A[(size_t)(bm + q * 8 + l3) * K + kt + srcg * 8], &Asw[q * 512]);
            gload16(&W[(size_t)(bn + q * 8 + l3) * K + kt + srcg * 8], &Bsw[q * 512]);
        }
        __syncthreads();

        #pragma unroll
        for (int kk = 0; kk < 2; ++kk) {
            const int s = (kk * 4 + hi) ^ l7;   // swizzled read granule
            short8 a[2], b[2];
            #pragma unroll
            for (int f = 0; f < 2; ++f) {
                a[f] = *(const short8*)&Asw[(wm * 32 + f * 16 + l15) * 64 + s * 8];
                b[f] = *(const short8*)&Bsw[(wn * 32 + f * 16 + l15) * 64 + s * 8];
            }
            #pragma unroll
            for (int i = 0; i < 2; ++i)
                #pragma unroll
                for (int j = 0; j < 2; ++j)
                    acc[i][j] = __builtin_amdgcn_mfma_f32_16x16x32_bf16(
                        a[i], b[j], acc[i][j], 0, 0, 0);
        }
        __syncthreads();
    }

    #pragma unroll
    for (int i = 0; i < 2; ++i) {
        #pragma unroll
        for (int j = 0; j < 2; ++j) {
            #pragma unroll
            for (int r = 0; r < 4; ++r) {
                const int m = bm + wm * 32 + i * 16 + hi * 4 + r;
                const int n = bn + wn * 32 + j * 16 + l15;
                float v = acc[i][j][r] + bias[n];
                if (ACT == 1) v = fmaxf(v, 0.f);
                if (RES) v += resid[(size_t)m * N + n];
                if (OBF16) ((ushort_t*)Cout)[(size_t)m * N + n] = f2b(v);
                else       ((float*)Cout)[(size_t)m * N + n] = v;
            }
        }
    }
}

// ---------------- Kt[b,h][d][j] = X[b,j,h*64+d] ----------------
__global__ __launch_bounds__(256) void transpose_kt(const float* __restrict__ X,
                                                    float* __restrict__ Kt)
{
    int o = blockIdx.x * 256 + threadIdx.x;
    int j = o & 511;
    int d = (o >> 9) & 63;
    int h = (o >> 15) & 7;
    int b = o >> 18;
    Kt[o] = X[((b << 9) + j) * 512 + h * 64 + d];
}

// ---------------- alpha per (b,h) ----------------
__global__ void alpha_kernel(const float* __restrict__ Q, const float* __restrict__ Wa,
                             const float* __restrict__ ba,
                             float* __restrict__ am1v, float* __restrict__ invv)
{
    int t = threadIdx.x;
    if (t >= BB * HH) return;
    int b = t >> 3, h = t & 7;
    float acc = 0.f;
    #pragma unroll
    for (int d = 0; d < HDIM; ++d)
        acc = fmaf(Q[((b << 9) + 511) * 512 + h * 64 + d], Wa[d], acc);
    acc += ba[0];
    float sig = 1.f / (1.f + expf(-acc));
    float alpha = sig + 1.f;
    const float amin = 1.f + 1e-5f;
    if (alpha < amin) alpha = amin;
    float am1 = alpha - 1.f;
    am1v[t] = am1;
    invv[t] = 1.f / am1;
}

// ---------------- fused attention v6: register Xs + 128-VGPR budget ----------------
// Occupancy is LDS-bound at 4 blocks/CU (= 4 waves/EU), so waves_per_eu(4,4)
// unlocks the full 512/4 = 128 VGPR budget -> Xs[32] fits with no scratch spill
// (R5/R6's 184 MB WRITE_SIZE was spill traffic under the compiler's 64-reg cap).
#define SLS 520
__attribute__((amdgpu_waves_per_eu(4, 4)))
__global__ __launch_bounds__(256) void attn_kernel(
    const float* __restrict__ Q, const float* __restrict__ X, const float* __restrict__ Kt,
    const float* __restrict__ mask, const float* __restrict__ am1v,
    const float* __restrict__ invv, float* __restrict__ ATT)
{
    __shared__ float qs[16][68];
    __shared__ float SL[16][SLS];      // scores -> unnormalized p; [row][512] = 1/S

    const int bid = ((blockIdx.x & 7) << 9) + (blockIdx.x >> 3);   // XCD swizzle
    const int bh = bid >> 5;
    const int rg = bid & 31;
    const int b = bh >> 3, h = bh & 7;
    const int tid = threadIdx.x;
    const int w = tid >> 6, lane = tid & 63;

    const float am1 = am1v[bh];
    const float inv = invv[bh];
    const float im1 = inv - 1.f;
    const float* KtBH = Kt + (size_t)bh * (64 * 512);

    // ---- phase A: stage q rows ----
    #pragma unroll
    for (int it = 0; it < 4; ++it) {
        int idx = tid + it * 256;
        int rr = idx >> 6, d = idx & 63;
        qs[rr][d] = Q[((b << 9) + rg * 16 + rr) * 512 + (h << 6) + d];
    }
    __syncthreads();   // the only barrier

    // ---- phase B: scores straight from global Kt; 2 chunks x 256 j ----
    #pragma unroll
    for (int c = 0; c < 2; ++c) {
        float acc[4][4] = {{0,0,0,0},{0,0,0,0},{0,0,0,0},{0,0,0,0}};
        const float* kp = KtBH + c * 256 + 4 * lane;
        #pragma unroll
        for (int d4 = 0; d4 < 16; ++d4) {
            float4 qv0 = *(const float4*)&qs[w*4+0][d4*4];
            float4 qv1 = *(const float4*)&qs[w*4+1][d4*4];
            float4 qv2 = *(const float4*)&qs[w*4+2][d4*4];
            float4 qv3 = *(const float4*)&qs[w*4+3][d4*4];
            #pragma unroll
            for (int dd = 0; dd < 4; ++dd) {
                float4 kv = *(const float4*)&kp[(size_t)(d4*4+dd) * 512];
                float q0 = dd==0?qv0.x:dd==1?qv0.y:dd==2?qv0.z:qv0.w;
                float q1 = dd==0?qv1.x:dd==1?qv1.y:dd==2?qv1.z:qv1.w;
                float q2 = dd==0?qv2.x:dd==1?qv2.y:dd==2?qv2.z:qv2.w;
                float q3 = dd==0?qv3.x:dd==1?qv3.y:dd==2?qv3.z:qv3.w;
                acc[0][0]=fmaf(q0,kv.x,acc[0][0]); acc[0][1]=fmaf(q0,kv.y,acc[0][1]);
                acc[0][2]=fmaf(q0,kv.z,acc[0][2]); acc[0][3]=fmaf(q0,kv.w,acc[0][3]);
                acc[1][0]=fmaf(q1,kv.x,acc[1][0]); acc[1][1]=fmaf(q1,kv.y,acc[1][1]);
                acc[1][2]=fmaf(q1,kv.z,acc[1][2]); acc[1][3]=fmaf(q1,kv.w,acc[1][3]);
                acc[2][0]=fmaf(q2,kv.x,acc[2][0]); acc[2][1]=fmaf(q2,kv.y,acc[2][1]);
                acc[2][2]=fmaf(q2,kv.z,acc[2][2]); acc[2][3]=fmaf(q2,kv.w,acc[2][3]);
                acc[3][0]=fmaf(q3,kv.x,acc[3][0]); acc[3][1]=fmaf(q3,kv.y,acc[3][1]);
                acc[3][2]=fmaf(q3,kv.z,acc[3][2]); acc[3][3]=fmaf(q3,kv.w,acc[3][3]);
            }
        }
        int jb = c * 256 + 4 * lane;
        *(float4*)&SL[w*4+0][jb] = make_float4(acc[0][0],acc[0][1],acc[0][2],acc[0][3]);
        *(float4*)&SL[w*4+1][jb] = make_float4(acc[1][0],acc[1][1],acc[1][2],acc[1][3]);
        *(float4*)&SL[w*4+2][jb] = make_float4(acc[2][0],acc[2][1],acc[2][2],acc[2][3]);
        *(float4*)&SL[w*4+3][jb] = make_float4(acc[3][0],acc[3][1],acc[3][2],acc[3][3]);
    }
    // intra-wave LDS dependency only -> no barrier

    // ---- phase C: entmax Newton, Xs register-resident ----
    const int lp = lane & 15, g = lane >> 4;
    const int row = w * 4 + g;
    const float NEG = -__builtin_inff();

    float Xs[32];
    #pragma unroll
    for (int e = 0; e < 32; ++e) {
        int j = e * 16 + lp;
        float sv = SL[row][j];
        float mv = (j < 511) ? mask[b * 511 + j] : 0.f;  // last key always masked
        Xs[e] = (mv == 0.f) ? NEG : sv * 0.125f * am1;
    }

    float mx = Xs[0];
    #pragma unroll
    for (int e = 1; e < 32; ++e) mx = fmaxf(mx, Xs[e]);
    mx = rmax16(mx);

    float tau = mx - 1.f;          // f(tau) >= 0 here; f convex decreasing
    for (int it = 0; it < NNEWT; ++it) {
        float s0=0.f,s1=0.f,s2=0.f,s3=0.f;
        float g0=0.f,g1=0.f,g2=0.f,g3=0.f;
        #pragma unroll
        for (int e = 0; e < 32; e += 4) {
            #pragma unroll
            for (int k = 0; k < 4; ++k) {
                float z  = Xs[e + k] - tau;
                float zc = fmaxf(z, 0.f);
                float dp = hw_exp2(im1 * hw_log2(zc));   // zc^(inv-1)
                dp = (zc > 0.f) ? dp : 0.f;              // guard im1==0 NaN
                float p  = dp * zc;
                if (k == 0) { s0 += p; g0 += dp; }
                else if (k == 1) { s1 += p; g1 += dp; }
                else if (k == 2) { s2 += p; g2 += dp; }
                else { s3 += p; g3 += dp; }
            }
        }
        float S  = rsum16((s0 + s1) + (s2 + s3));
        float Sp = rsum16((g0 + g1) + (g2 + g3));
        tau += (S - 1.f) / (inv * Sp);
    }

    // final eval: write UNNORMALIZED p to SL (streaming); 1/S at SL[row][512]
    {
        float s0=0.f,s1=0.f,s2=0.f,s3=0.f;
        #pragma unroll
        for (int e = 0; e < 32; e += 4) {
            #pragma unroll
            for (int k = 0; k < 4; ++k) {
                float zc = fmaxf(Xs[e + k] - tau, 0.f);
                float p  = hw_exp2(inv * hw_log2(zc));   // inv>=1: exp2(-inf)=0
                SL[row][(e + k) * 16 + lp] = p;
                if (k == 0) s0 += p; else if (k == 1) s1 += p;
                else if (k == 2) s2 += p; else s3 += p;
            }
        }
        float S = rsum16((s0 + s1) + (s2 + s3));
        if (lp == 0) SL[row][512] = 1.f / S;
    }
    // intra-wave only -> no barrier

    // ---- phase D: PV straight from global X ----
    float att0 = 0.f, att1 = 0.f, att2 = 0.f, att3 = 0.f;
    const float* xp = X + (size_t)(b << 9) * 512 + (h << 6) + lane;
    #pragma unroll 4
    for (int j4 = 0; j4 < 128; ++j4) {
        float4 p0 = *(const float4*)&SL[w*4+0][j4*4];
        float4 p1 = *(const float4*)&SL[w*4+1][j4*4];
        float4 p2 = *(const float4*)&SL[w*4+2][j4*4];
        float4 p3 = *(const float4*)&SL[w*4+3][j4*4];
        #pragma unroll
        for (int qq = 0; qq < 4; ++qq) {
            float xv = xp[(size_t)(j4*4+qq) * 512];
            float pq0 = qq==0?p0.x:qq==1?p0.y:qq==2?p0.z:p0.w;
            float pq1 = qq==0?p1.x:qq==1?p1.y:qq==2?p1.z:p1.w;
            float pq2 = qq==0?p2.x:qq==1?p2.y:qq==2?p2.z:p2.w;
            float pq3 = qq==0?p3.x:qq==1?p3.y:qq==2?p3.z:p3.w;
            att0 = fmaf(pq0, xv, att0);
            att1 = fmaf(pq1, xv, att1);
            att2 = fmaf(pq2, xv, att2);
            att3 = fmaf(pq3, xv, att3);
        }
    }
    att0 *= SL[w*4+0][512];
    att1 *= SL[w*4+1][512];
    att2 *= SL[w*4+2][512];
    att3 *= SL[w*4+3][512];

    {
        int ibase = rg * 16 + w * 4;
        ATT[((size_t)(b << 9) + ibase + 0) * 512 + (h << 6) + lane] = att0;
        ATT[((size_t)(b << 9) + ibase + 1) * 512 + (h << 6) + lane] = att1;
        ATT[((size_t)(b << 9) + ibase + 2) * 512 + (h << 6) + lane] = att2;
        ATT[((size_t)(b << 9) + ibase + 3) * 512 + (h << 6) + lane] = att3;
    }
}

// ---------------- LayerNorm + scatter ----------------
__global__ __launch_bounds__(256) void ln_kernel(const float* __restrict__ Cb,
                                                 const float* __restrict__ g,
                                                 const float* __restrict__ beta,
                                                 float* __restrict__ out)
{
    const int w = threadIdx.x >> 6, lane = threadIdx.x & 63;
    const int row = blockIdx.x * 4 + w;
    const int b = row >> 9, l = row & 511;
    const float* x = Cb + (size_t)row * 512;

    float v[8], s = 0.f;
    #pragma unroll
    for (int k = 0; k < 8; ++k) { v[k] = x[k * 64 + lane]; s += v[k]; }
    s = wsum(s);
    float mu = s * (1.f / 512.f);
    float q = 0.f;
    #pragma unroll
    for (int k = 0; k < 8; ++k) { float d = v[k] - mu; q = fmaf(d, d, q); }
    q = wsum(q);
    float rs = rsqrtf(q * (1.f / 512.f) + 1e-12f);

    float* dst = (l < 511) ? (out + (size_t)(b * 511 + l) * 512)
                           : (out + (size_t)16 * 511 * 512 + (size_t)b * 512);
    #pragma unroll
    for (int k = 0; k < 8; ++k) {
        int d = k * 64 + lane;
        dst[d] = (v[k] - mu) * rs * g[d] + beta[d];
    }
}

// ---------------- launch ----------------
extern "C" void kernel_launch(void* const* d_in, const int* in_sizes, int n_in,
                              void* d_out, int out_size, void* d_ws, size_t ws_size,
                              hipStream_t stream)
{
    const float* X    = (const float*)d_in[0];
    const float* mask = (const float*)d_in[1];
    const float* Wq   = (const float*)d_in[2];
    const float* bq   = (const float*)d_in[3];
    const float* W1   = (const float*)d_in[4];
    const float* b1   = (const float*)d_in[5];
    const float* W2   = (const float*)d_in[6];
    const float* b2   = (const float*)d_in[7];
    const float* lng  = (const float*)d_in[8];
    const float* lnb  = (const float*)d_in[9];
    const float* Wa   = (const float*)d_in[10];
    const float* ba   = (const float*)d_in[11];
    float* out = (float*)d_out;
    float* ws  = (float*)d_ws;

    const size_t NE = (size_t)BB * LL * DD;      // 4194304
    const size_t WN = (size_t)DD * DD;           // 262144
    if (ws_size < (3 * NE + 256) * sizeof(float) + 3 * WN * sizeof(ushort_t)) return;

    float* Qb   = ws;
    float* Kt   = ws + NE;
    float* ATT  = ws + 2 * NE;
    float* am1v = ws + 3 * NE;
    float* invv = am1v + 128;
    ushort_t* Wqb = (ushort_t*)(am1v + 256);
    ushort_t* W1b = Wqb + WN;
    ushort_t* W2b = W1b + WN;
    ushort_t* Xb   = (ushort_t*)ATT;
    ushort_t* ATTb = (ushort_t*)Qb;
    ushort_t* Hhb  = (ushort_t*)Qb + NE;
    float* Cb = Kt;

    const int M = BB * LL;       // 8192

    conv_f2b<<<(int)(NE / 1024), 256, 0, stream>>>(X, Xb);
    conv_f2b<<<(int)(WN / 1024), 256, 0, stream>>>(Wq, Wqb);
    gemm_mfma<1, false, false><<<dim3(DD / 64, M / 64), 256, 0, stream>>>(
        Xb, Wqb, bq, nullptr, Qb, M, DD, DD);
    transpose_kt<<<(int)(NE / 256), 256, 0, stream>>>(X, Kt);
    alpha_kernel<<<1, 128, 0, stream>>>(Qb, Wa, ba, am1v, invv);
    attn_kernel<<<BB * HH * LL / 16, 256, 0, stream>>>(Qb, X, Kt, mask, am1v, invv, ATT);
    conv_f2b<<<(int)(NE / 1024), 256, 0, stream>>>(ATT, ATTb);
    conv_f2b<<<(int)(WN / 1024), 256, 0, stream>>>(W1, W1b);
    gemm_mfma<1, false, true><<<dim3(DD / 64, M / 64), 256, 0, stream>>>(
        ATTb, W1b, b1, nullptr, Hhb, M, DD, DD);
    conv_f2b<<<(int)(WN / 1024), 256, 0, stream>>>(W2, W2b);
    gemm_mfma<0, true, false><<<dim3(DD / 64, M / 64), 256, 0, stream>>>(
        Hhb, W2b, b2, ATT, Cb, M, DD, DD);
    ln_kernel<<<M / 4, 256, 0, stream>>>(Cb, lng, lnb, out);
}

// Round 8
// 392.842 us; speedup vs baseline: 1.0281x; 1.0281x over previous
//
#include <hip/hip_runtime.h>
#include <math.h>

#define BB   16
#define LL   512
#define DD   512
#define HH   8
#define HDIM 64
#define NNEWT 12

typedef unsigned short ushort_t;
typedef __attribute__((ext_vector_type(8))) short short8;
typedef __attribute__((ext_vector_type(4))) float f32x4;

// raw single-instruction transcendentals
__device__ __forceinline__ float hw_log2(float x) { return __builtin_amdgcn_logf(x); }
__device__ __forceinline__ float hw_exp2(float x) { return __builtin_amdgcn_exp2f(x); }

__device__ __forceinline__ ushort_t f2b(float f) {
    unsigned u = __builtin_bit_cast(unsigned, f);
    unsigned r = u + 0x7FFFu + ((u >> 16) & 1u);     // RNE
    return (ushort_t)(r >> 16);
}

// ---------------- wave-wide reduction (64 lanes) for ln ----------------
__device__ __forceinline__ float wsum(float v) {
    v += __shfl_xor(v, 1);  v += __shfl_xor(v, 2);  v += __shfl_xor(v, 4);
    v += __shfl_xor(v, 8);  v += __shfl_xor(v, 16); v += __shfl_xor(v, 32);
    return v;
}

// ---------------- DPP butterflies ----------------
template<int CTRL>
__device__ __forceinline__ float dpp_mov(float v) {
    return __builtin_bit_cast(float, __builtin_amdgcn_update_dpp(
        0, __builtin_bit_cast(int, v), CTRL, 0xf, 0xf, true));
}
// sum/max over 32-lane group: 4 DPP steps (within 16) + lane^16 shuffle
__device__ __forceinline__ float rsum32(float v) {
    v += dpp_mov<0xB1>(v);    // quad_perm xor1
    v += dpp_mov<0x4E>(v);    // quad_perm xor2
    v += dpp_mov<0x141>(v);   // row_half_mirror (acts as xor4 after prior steps)
    v += dpp_mov<0x140>(v);   // row_mirror      (acts as xor8)
    v += __shfl_xor(v, 16);   // cross-16 within the 32-group
    return v;
}
__device__ __forceinline__ float rmax32(float v) {
    v = fmaxf(v, dpp_mov<0xB1>(v));
    v = fmaxf(v, dpp_mov<0x4E>(v));
    v = fmaxf(v, dpp_mov<0x141>(v));
    v = fmaxf(v, dpp_mov<0x140>(v));
    v = fmaxf(v, __shfl_xor(v, 16));
    return v;
}

// ---------------- fp32 -> bf16 conversion (memory-bound) ----------------
__global__ __launch_bounds__(256) void conv_f2b(const float* __restrict__ in,
                                                ushort_t* __restrict__ out)
{
    int i = (blockIdx.x * 256 + threadIdx.x) * 4;
    float4 v = *(const float4*)&in[i];
    ushort4 o;
    o.x = f2b(v.x); o.y = f2b(v.y); o.z = f2b(v.z); o.w = f2b(v.w);
    *(ushort4*)&out[i] = o;
}

// ---------------- bf16 MFMA GEMM: C = act(A @ W^T + bias) [+ resid] ----------------
__device__ __forceinline__ void gload16(const void* g, void* l) {
    __builtin_amdgcn_global_load_lds(
        (const __attribute__((address_space(1))) unsigned*)g,
        (__attribute__((address_space(3))) unsigned*)l, 16, 0, 0);
}

template<int ACT, bool RES, bool OBF16>
__global__ __launch_bounds__(256) void gemm_mfma(
    const ushort_t* __restrict__ A, const ushort_t* __restrict__ W,
    const float* __restrict__ bias, const float* __restrict__ resid,
    void* __restrict__ Cout, int M, int N, int K)
{
    __shared__ ushort_t Asw[64 * 64];
    __shared__ ushort_t Bsw[64 * 64];

    const int tid = threadIdx.x;
    const int w = tid >> 6, lane = tid & 63;
    const int wm = w >> 1, wn = w & 1;
    const int bm = blockIdx.y * 64, bn = blockIdx.x * 64;

    const int l3 = lane >> 3, l7 = lane & 7;
    const int srcg = l7 ^ l3;               // pre-swizzled source granule
    const int l15 = lane & 15, hi = lane >> 4;

    f32x4 acc[2][2] = {};

    for (int kt = 0; kt < K; kt += 64) {
        #pragma unroll
        for (int u = 0; u < 2; ++u) {
            int q = w * 2 + u;
            gload16(&A[(size_t)(bm + q * 8 + l3) * K + kt + srcg * 8], &Asw[q * 512]);
            gload16(&W[(size_t)(bn + q * 8 + l3) * K + kt + srcg * 8], &Bsw[q * 512]);
        }
        __syncthreads();

        #pragma unroll
        for (int kk = 0; kk < 2; ++kk) {
            const int s = (kk * 4 + hi) ^ l7;   // swizzled read granule
            short8 a[2], b[2];
            #pragma unroll
            for (int f = 0; f < 2; ++f) {
                a[f] = *(const short8*)&Asw[(wm * 32 + f * 16 + l15) * 64 + s * 8];
                b[f] = *(const short8*)&Bsw[(wn * 32 + f * 16 + l15) * 64 + s * 8];
            }
            #pragma unroll
            for (int i = 0; i < 2; ++i)
                #pragma unroll
                for (int j = 0; j < 2; ++j)
                    acc[i][j] = __builtin_amdgcn_mfma_f32_16x16x32_bf16(
                        a[i], b[j], acc[i][j], 0, 0, 0);
        }
        __syncthreads();
    }

    #pragma unroll
    for (int i = 0; i < 2; ++i) {
        #pragma unroll
        for (int j = 0; j < 2; ++j) {
            #pragma unroll
            for (int r = 0; r < 4; ++r) {
                const int m = bm + wm * 32 + i * 16 + hi * 4 + r;
                const int n = bn + wn * 32 + j * 16 + l15;
                float v = acc[i][j][r] + bias[n];
                if (ACT == 1) v = fmaxf(v, 0.f);
                if (RES) v += resid[(size_t)m * N + n];
                if (OBF16) ((ushort_t*)Cout)[(size_t)m * N + n] = f2b(v);
                else       ((float*)Cout)[(size_t)m * N + n] = v;
            }
        }
    }
}

// ---------------- Kt[b,h][d][j] = X[b,j,h*64+d] ----------------
__global__ __launch_bounds__(256) void transpose_kt(const float* __restrict__ X,
                                                    float* __restrict__ Kt)
{
    int o = blockIdx.x * 256 + threadIdx.x;
    int j = o & 511;
    int d = (o >> 9) & 63;
    int h = (o >> 15) & 7;
    int b = o >> 18;
    Kt[o] = X[((b << 9) + j) * 512 + h * 64 + d];
}

// ---------------- alpha per (b,h) ----------------
__global__ void alpha_kernel(const float* __restrict__ Q, const float* __restrict__ Wa,
                             const float* __restrict__ ba,
                             float* __restrict__ am1v, float* __restrict__ invv)
{
    int t = threadIdx.x;
    if (t >= BB * HH) return;
    int b = t >> 3, h = t & 7;
    float acc = 0.f;
    #pragma unroll
    for (int d = 0; d < HDIM; ++d)
        acc = fmaf(Q[((b << 9) + 511) * 512 + h * 64 + d], Wa[d], acc);
    acc += ba[0];
    float sig = 1.f / (1.f + expf(-acc));
    float alpha = sig + 1.f;
    const float amin = 1.f + 1e-5f;
    if (alpha < amin) alpha = amin;
    float am1 = alpha - 1.f;
    am1v[t] = am1;
    invv[t] = 1.f / am1;
}

// ---------------- fused attention v7: 32-lane-group Newton, Xs[16] ----------------
// Phase C working set shrunk to fit the allocator's 64-VGPR budget:
// each wave solves its 4 rows in 2 sequential passes; per pass, two 32-lane
// groups each own one row with 16 elements/lane (Xs[16] + ~12 temps ~ 45 regs).
#define SLS 520
__global__ __launch_bounds__(256, 4) void attn_kernel(
    const float* __restrict__ Q, const float* __restrict__ X, const float* __restrict__ Kt,
    const float* __restrict__ mask, const float* __restrict__ am1v,
    const float* __restrict__ invv, float* __restrict__ ATT)
{
    __shared__ float qs[16][68];
    __shared__ float SL[16][SLS];      // scores -> unnormalized p; [row][512] = 1/S

    const int bid = ((blockIdx.x & 7) << 9) + (blockIdx.x >> 3);   // XCD swizzle
    const int bh = bid >> 5;
    const int rg = bid & 31;
    const int b = bh >> 3, h = bh & 7;
    const int tid = threadIdx.x;
    const int w = tid >> 6, lane = tid & 63;

    const float am1 = am1v[bh];
    const float inv = invv[bh];
    const float im1 = inv - 1.f;
    const float* KtBH = Kt + (size_t)bh * (64 * 512);

    // ---- phase A: stage q rows ----
    #pragma unroll
    for (int it = 0; it < 4; ++it) {
        int idx = tid + it * 256;
        int rr = idx >> 6, d = idx & 63;
        qs[rr][d] = Q[((b << 9) + rg * 16 + rr) * 512 + (h << 6) + d];
    }
    __syncthreads();   // the only barrier

    // ---- phase B: scores straight from global Kt; 2 chunks x 256 j ----
    #pragma unroll
    for (int c = 0; c < 2; ++c) {
        float acc[4][4] = {{0,0,0,0},{0,0,0,0},{0,0,0,0},{0,0,0,0}};
        const float* kp = KtBH + c * 256 + 4 * lane;
        #pragma unroll
        for (int d4 = 0; d4 < 16; ++d4) {
            float4 qv0 = *(const float4*)&qs[w*4+0][d4*4];
            float4 qv1 = *(const float4*)&qs[w*4+1][d4*4];
            float4 qv2 = *(const float4*)&qs[w*4+2][d4*4];
            float4 qv3 = *(const float4*)&qs[w*4+3][d4*4];
            #pragma unroll
            for (int dd = 0; dd < 4; ++dd) {
                float4 kv = *(const float4*)&kp[(size_t)(d4*4+dd) * 512];
                float q0 = dd==0?qv0.x:dd==1?qv0.y:dd==2?qv0.z:qv0.w;
                float q1 = dd==0?qv1.x:dd==1?qv1.y:dd==2?qv1.z:qv1.w;
                float q2 = dd==0?qv2.x:dd==1?qv2.y:dd==2?qv2.z:qv2.w;
                float q3 = dd==0?qv3.x:dd==1?qv3.y:dd==2?qv3.z:qv3.w;
                acc[0][0]=fmaf(q0,kv.x,acc[0][0]); acc[0][1]=fmaf(q0,kv.y,acc[0][1]);
                acc[0][2]=fmaf(q0,kv.z,acc[0][2]); acc[0][3]=fmaf(q0,kv.w,acc[0][3]);
                acc[1][0]=fmaf(q1,kv.x,acc[1][0]); acc[1][1]=fmaf(q1,kv.y,acc[1][1]);
                acc[1][2]=fmaf(q1,kv.z,acc[1][2]); acc[1][3]=fmaf(q1,kv.w,acc[1][3]);
                acc[2][0]=fmaf(q2,kv.x,acc[2][0]); acc[2][1]=fmaf(q2,kv.y,acc[2][1]);
                acc[2][2]=fmaf(q2,kv.z,acc[2][2]); acc[2][3]=fmaf(q2,kv.w,acc[2][3]);
                acc[3][0]=fmaf(q3,kv.x,acc[3][0]); acc[3][1]=fmaf(q3,kv.y,acc[3][1]);
                acc[3][2]=fmaf(q3,kv.z,acc[3][2]); acc[3][3]=fmaf(q3,kv.w,acc[3][3]);
            }
        }
        int jb = c * 256 + 4 * lane;
        *(float4*)&SL[w*4+0][jb] = make_float4(acc[0][0],acc[0][1],acc[0][2],acc[0][3]);
        *(float4*)&SL[w*4+1][jb] = make_float4(acc[1][0],acc[1][1],acc[1][2],acc[1][3]);
        *(float4*)&SL[w*4+2][jb] = make_float4(acc[2][0],acc[2][1],acc[2][2],acc[2][3]);
        *(float4*)&SL[w*4+3][jb] = make_float4(acc[3][0],acc[3][1],acc[3][2],acc[3][3]);
    }
    // intra-wave LDS dependency only -> no barrier

    // ---- phase C: entmax Newton; 2 passes x (two 32-lane groups, 1 row each) ----
    const int l5 = lane & 31, gg = lane >> 5;
    const float NEG = -__builtin_inff();
    const float sc = 0.125f * am1;

    #pragma unroll
    for (int pp = 0; pp < 2; ++pp) {
        const int row = w * 4 + pp * 2 + gg;

        float Xs[16];
        #pragma unroll
        for (int e = 0; e < 16; ++e) {
            int j = e * 32 + l5;
            float sv = SL[row][j];
            float mv = (j < 511) ? mask[b * 511 + j] : 0.f;  // last key always masked
            Xs[e] = (mv == 0.f) ? NEG : sv * sc;
        }

        float mx = Xs[0];
        #pragma unroll
        for (int e = 1; e < 16; ++e) mx = fmaxf(mx, Xs[e]);
        mx = rmax32(mx);

        float tau = mx - 1.f;      // f(tau) >= 0 here; f convex decreasing
        for (int it = 0; it < NNEWT; ++it) {
            float s0 = 0.f, s1 = 0.f, g0 = 0.f, g1 = 0.f;
            #pragma unroll
            for (int e = 0; e < 16; e += 2) {
                float za = fmaxf(Xs[e]     - tau, 0.f);
                float zb = fmaxf(Xs[e + 1] - tau, 0.f);
                float da = hw_exp2(im1 * hw_log2(za));   // za^(inv-1)
                float db = hw_exp2(im1 * hw_log2(zb));
                da = (za > 0.f) ? da : 0.f;              // guard im1==0 NaN
                db = (zb > 0.f) ? db : 0.f;
                s0 += da * za; g0 += da;
                s1 += db * zb; g1 += db;
            }
            float S  = rsum32(s0 + s1);
            float Sp = rsum32(g0 + g1);
            tau += (S - 1.f) / (inv * Sp);
        }

        // final eval: unnormalized p -> SL; 1/S at SL[row][512]
        float s0 = 0.f, s1 = 0.f;
        #pragma unroll
        for (int e = 0; e < 16; e += 2) {
            float za = fmaxf(Xs[e]     - tau, 0.f);
            float zb = fmaxf(Xs[e + 1] - tau, 0.f);
            float pa = hw_exp2(inv * hw_log2(za));       // inv>=1: exp2(-inf)=0
            float pb = hw_exp2(inv * hw_log2(zb));
            SL[row][e * 32 + l5]       = pa;
            SL[row][(e + 1) * 32 + l5] = pb;
            s0 += pa; s1 += pb;
        }
        float S = rsum32(s0 + s1);
        if (l5 == 0) SL[row][512] = 1.f / S;
    }
    // intra-wave only -> no barrier

    // ---- phase D: PV straight from global X ----
    float att0 = 0.f, att1 = 0.f, att2 = 0.f, att3 = 0.f;
    const float* xp = X + (size_t)(b << 9) * 512 + (h << 6) + lane;
    #pragma unroll 4
    for (int j4 = 0; j4 < 128; ++j4) {
        float4 p0 = *(const float4*)&SL[w*4+0][j4*4];
        float4 p1 = *(const float4*)&SL[w*4+1][j4*4];
        float4 p2 = *(const float4*)&SL[w*4+2][j4*4];
        float4 p3 = *(const float4*)&SL[w*4+3][j4*4];
        #pragma unroll
        for (int qq = 0; qq < 4; ++qq) {
            float xv = xp[(size_t)(j4*4+qq) * 512];
            float pq0 = qq==0?p0.x:qq==1?p0.y:qq==2?p0.z:p0.w;
            float pq1 = qq==0?p1.x:qq==1?p1.y:qq==2?p1.z:p1.w;
            float pq2 = qq==0?p2.x:qq==1?p2.y:qq==2?p2.z:p2.w;
            float pq3 = qq==0?p3.x:qq==1?p3.y:qq==2?p3.z:p3.w;
            att0 = fmaf(pq0, xv, att0);
            att1 = fmaf(pq1, xv, att1);
            att2 = fmaf(pq2, xv, att2);
            att3 = fmaf(pq3, xv, att3);
        }
    }
    att0 *= SL[w*4+0][512];
    att1 *= SL[w*4+1][512];
    att2 *= SL[w*4+2][512];
    att3 *= SL[w*4+3][512];

    {
        int ibase = rg * 16 + w * 4;
        ATT[((size_t)(b << 9) + ibase + 0) * 512 + (h << 6) + lane] = att0;
        ATT[((size_t)(b << 9) + ibase + 1) * 512 + (h << 6) + lane] = att1;
        ATT[((size_t)(b << 9) + ibase + 2) * 512 + (h << 6) + lane] = att2;
        ATT[((size_t)(b << 9) + ibase + 3) * 512 + (h << 6) + lane] = att3;
    }
}

// ---------------- LayerNorm + scatter ----------------
__global__ __launch_bounds__(256) void ln_kernel(const float* __restrict__ Cb,
                                                 const float* __restrict__ g,
                                                 const float* __restrict__ beta,
                                                 float* __restrict__ out)
{
    const int w = threadIdx.x >> 6, lane = threadIdx.x & 63;
    const int row = blockIdx.x * 4 + w;
    const int b = row >> 9, l = row & 511;
    const float* x = Cb + (size_t)row * 512;

    float v[8], s = 0.f;
    #pragma unroll
    for (int k = 0; k < 8; ++k) { v[k] = x[k * 64 + lane]; s += v[k]; }
    s = wsum(s);
    float mu = s * (1.f / 512.f);
    float q = 0.f;
    #pragma unroll
    for (int k = 0; k < 8; ++k) { float d = v[k] - mu; q = fmaf(d, d, q); }
    q = wsum(q);
    float rs = rsqrtf(q * (1.f / 512.f) + 1e-12f);

    float* dst = (l < 511) ? (out + (size_t)(b * 511 + l) * 512)
                           : (out + (size_t)16 * 511 * 512 + (size_t)b * 512);
    #pragma unroll
    for (int k = 0; k < 8; ++k) {
        int d = k * 64 + lane;
        dst[d] = (v[k] - mu) * rs * g[d] + beta[d];
    }
}

// ---------------- launch ----------------
extern "C" void kernel_launch(void* const* d_in, const int* in_sizes, int n_in,
                              void* d_out, int out_size, void* d_ws, size_t ws_size,
                              hipStream_t stream)
{
    const float* X    = (const float*)d_in[0];
    const float* mask = (const float*)d_in[1];
    const float* Wq   = (const float*)d_in[2];
    const float* bq   = (const float*)d_in[3];
    const float* W1   = (const float*)d_in[4];
    const float* b1   = (const float*)d_in[5];
    const float* W2   = (const float*)d_in[6];
    const float* b2   = (const float*)d_in[7];
    const float* lng  = (const float*)d_in[8];
    const float* lnb  = (const float*)d_in[9];
    const float* Wa   = (const float*)d_in[10];
    const float* ba   = (const float*)d_in[11];
    float* out = (float*)d_out;
    float* ws  = (float*)d_ws;

    const size_t NE = (size_t)BB * LL * DD;      // 4194304
    const size_t WN = (size_t)DD * DD;           // 262144
    if (ws_size < (3 * NE + 256) * sizeof(float) + 3 * WN * sizeof(ushort_t)) return;

    float* Qb   = ws;
    float* Kt   = ws + NE;
    float* ATT  = ws + 2 * NE;
    float* am1v = ws + 3 * NE;
    float* invv = am1v + 128;
    ushort_t* Wqb = (ushort_t*)(am1v + 256);
    ushort_t* W1b = Wqb + WN;
    ushort_t* W2b = W1b + WN;
    ushort_t* Xb   = (ushort_t*)ATT;
    ushort_t* ATTb = (ushort_t*)Qb;
    ushort_t* Hhb  = (ushort_t*)Qb + NE;
    float* Cb = Kt;

    const int M = BB * LL;       // 8192

    conv_f2b<<<(int)(NE / 1024), 256, 0, stream>>>(X, Xb);
    conv_f2b<<<(int)(WN / 1024), 256, 0, stream>>>(Wq, Wqb);
    gemm_mfma<1, false, false><<<dim3(DD / 64, M / 64), 256, 0, stream>>>(
        Xb, Wqb, bq, nullptr, Qb, M, DD, DD);
    transpose_kt<<<(int)(NE / 256), 256, 0, stream>>>(X, Kt);
    alpha_kernel<<<1, 128, 0, stream>>>(Qb, Wa, ba, am1v, invv);
    attn_kernel<<<BB * HH * LL / 16, 256, 0, stream>>>(Qb, X, Kt, mask, am1v, invv, ATT);
    conv_f2b<<<(int)(NE / 1024), 256, 0, stream>>>(ATT, ATTb);
    conv_f2b<<<(int)(WN / 1024), 256, 0, stream>>>(W1, W1b);
    gemm_mfma<1, false, true><<<dim3(DD / 64, M / 64), 256, 0, stream>>>(
        ATTb, W1b, b1, nullptr, Hhb, M, DD, DD);
    conv_f2b<<<(int)(WN / 1024), 256, 0, stream>>>(W2, W2b);
    gemm_mfma<0, true, false><<<dim3(DD / 64, M / 64), 256, 0, stream>>>(
        Hhb, W2b, b2, ATT, Cb, M, DD, DD);
    ln_kernel<<<M / 4, 256, 0, stream>>>(Cb, lng, lnb, out);
}

// Round 9
// 246.084 us; speedup vs baseline: 1.6412x; 1.5964x over previous
//
#include <hip/hip_runtime.h>
#include <math.h>

#define BB   16
#define LL   512
#define DD   512
#define HH   8
#define HDIM 64
#define NNEWT 12

typedef unsigned short ushort_t;
typedef __attribute__((ext_vector_type(8))) short short8;
typedef __attribute__((ext_vector_type(4))) float f32x4;

// raw single-instruction transcendentals
__device__ __forceinline__ float hw_log2(float x) { return __builtin_amdgcn_logf(x); }
__device__ __forceinline__ float hw_exp2(float x) { return __builtin_amdgcn_exp2f(x); }

__device__ __forceinline__ ushort_t f2b(float f) {
    unsigned u = __builtin_bit_cast(unsigned, f);
    unsigned r = u + 0x7FFFu + ((u >> 16) & 1u);     // RNE
    return (ushort_t)(r >> 16);
}

// ---------------- wave-wide reduction (64 lanes) for ln ----------------
__device__ __forceinline__ float wsum(float v) {
    v += __shfl_xor(v, 1);  v += __shfl_xor(v, 2);  v += __shfl_xor(v, 4);
    v += __shfl_xor(v, 8);  v += __shfl_xor(v, 16); v += __shfl_xor(v, 32);
    return v;
}

// ---------------- DPP butterflies ----------------
template<int CTRL>
__device__ __forceinline__ float dpp_mov(float v) {
    return __builtin_bit_cast(float, __builtin_amdgcn_update_dpp(
        0, __builtin_bit_cast(int, v), CTRL, 0xf, 0xf, true));
}
__device__ __forceinline__ float rsum32(float v) {
    v += dpp_mov<0xB1>(v);
    v += dpp_mov<0x4E>(v);
    v += dpp_mov<0x141>(v);
    v += dpp_mov<0x140>(v);
    v += __shfl_xor(v, 16);
    return v;
}
__device__ __forceinline__ float rmax32(float v) {
    v = fmaxf(v, dpp_mov<0xB1>(v));
    v = fmaxf(v, dpp_mov<0x4E>(v));
    v = fmaxf(v, dpp_mov<0x141>(v));
    v = fmaxf(v, dpp_mov<0x140>(v));
    v = fmaxf(v, __shfl_xor(v, 16));
    return v;
}

// ---------------- fp32 -> bf16 conversion (memory-bound) ----------------
__global__ __launch_bounds__(256) void conv_f2b(const float* __restrict__ in,
                                                ushort_t* __restrict__ out)
{
    int i = (blockIdx.x * 256 + threadIdx.x) * 4;
    float4 v = *(const float4*)&in[i];
    ushort4 o;
    o.x = f2b(v.x); o.y = f2b(v.y); o.z = f2b(v.z); o.w = f2b(v.w);
    *(ushort4*)&out[i] = o;
}

// ---------------- bf16 MFMA GEMM: C = act(A @ W^T + bias) [+ resid] ----------------
__device__ __forceinline__ void gload16(const void* g, void* l) {
    __builtin_amdgcn_global_load_lds(
        (const __attribute__((address_space(1))) unsigned*)g,
        (__attribute__((address_space(3))) unsigned*)l, 16, 0, 0);
}

template<int ACT, bool RES, bool OBF16>
__global__ __launch_bounds__(256) void gemm_mfma(
    const ushort_t* __restrict__ A, const ushort_t* __restrict__ W,
    const float* __restrict__ bias, const float* __restrict__ resid,
    void* __restrict__ Cout, int M, int N, int K)
{
    __shared__ ushort_t Asw[64 * 64];
    __shared__ ushort_t Bsw[64 * 64];

    const int tid = threadIdx.x;
    const int w = tid >> 6, lane = tid & 63;
    const int wm = w >> 1, wn = w & 1;
    const int bm = blockIdx.y * 64, bn = blockIdx.x * 64;

    const int l3 = lane >> 3, l7 = lane & 7;
    const int srcg = l7 ^ l3;               // pre-swizzled source granule
    const int l15 = lane & 15, hi = lane >> 4;

    f32x4 acc[2][2] = {};

    for (int kt = 0; kt < K; kt += 64) {
        #pragma unroll
        for (int u = 0; u < 2; ++u) {
            int q = w * 2 + u;
            gload16(&A[(size_t)(bm + q * 8 + l3) * K + kt + srcg * 8], &Asw[q * 512]);
            gload16(&W[(size_t)(bn + q * 8 + l3) * K + kt + srcg * 8], &Bsw[q * 512]);
        }
        __syncthreads();

        #pragma unroll
        for (int kk = 0; kk < 2; ++kk) {
            const int s = (kk * 4 + hi) ^ l7;   // swizzled read granule
            short8 a[2], b[2];
            #pragma unroll
            for (int f = 0; f < 2; ++f) {
                a[f] = *(const short8*)&Asw[(wm * 32 + f * 16 + l15) * 64 + s * 8];
                b[f] = *(const short8*)&Bsw[(wn * 32 + f * 16 + l15) * 64 + s * 8];
            }
            #pragma unroll
            for (int i = 0; i < 2; ++i)
                #pragma unroll
                for (int j = 0; j < 2; ++j)
                    acc[i][j] = __builtin_amdgcn_mfma_f32_16x16x32_bf16(
                        a[i], b[j], acc[i][j], 0, 0, 0);
        }
        __syncthreads();
    }

    #pragma unroll
    for (int i = 0; i < 2; ++i) {
        #pragma unroll
        for (int j = 0; j < 2; ++j) {
            #pragma unroll
            for (int r = 0; r < 4; ++r) {
                const int m = bm + wm * 32 + i * 16 + hi * 4 + r;
                const int n = bn + wn * 32 + j * 16 + l15;
                float v = acc[i][j][r] + bias[n];
                if (ACT == 1) v = fmaxf(v, 0.f);
                if (RES) v += resid[(size_t)m * N + n];
                if (OBF16) ((ushort_t*)Cout)[(size_t)m * N + n] = f2b(v);
                else       ((float*)Cout)[(size_t)m * N + n] = v;
            }
        }
    }
}

// ---------------- Ktb[b,h][d][j] = Xb[b,j,h*64+d] (bf16 in, bf16 out) ----------------
__global__ __launch_bounds__(256) void transpose_kt(const ushort_t* __restrict__ Xb,
                                                    ushort_t* __restrict__ Ktb)
{
    int o = blockIdx.x * 256 + threadIdx.x;
    int j = o & 511;
    int d = (o >> 9) & 63;
    int h = (o >> 15) & 7;
    int b = o >> 18;
    Ktb[o] = Xb[((b << 9) + j) * 512 + h * 64 + d];
}

// ---------------- alpha per (b,h) ----------------
__global__ void alpha_kernel(const float* __restrict__ Q, const float* __restrict__ Wa,
                             const float* __restrict__ ba,
                             float* __restrict__ am1v, float* __restrict__ invv)
{
    int t = threadIdx.x;
    if (t >= BB * HH) return;
    int b = t >> 3, h = t & 7;
    float acc = 0.f;
    #pragma unroll
    for (int d = 0; d < HDIM; ++d)
        acc = fmaf(Q[((b << 9) + 511) * 512 + h * 64 + d], Wa[d], acc);
    acc += ba[0];
    float sig = 1.f / (1.f + expf(-acc));
    float alpha = sig + 1.f;
    const float amin = 1.f + 1e-5f;
    if (alpha < amin) alpha = amin;
    float am1 = alpha - 1.f;
    am1v[t] = am1;
    invv[t] = 1.f / am1;
}

// ---------------- fused attention v8: MFMA QK^T + PV, Newton in 32-lane groups ----
// Phase B: S^T = K·Q^T via mfma (A = Xb rows [j][d] contiguous dwordx4,
//          B = bf16 Q tile in LDS). D layout: col(lane&15)=q, row(hi*4+r)=j.
// Phase C: v7 Newton (Xs[16] per 32-lane group); final eval writes P as bf16
//          in-place into SL rows (bytes [0,1024) of each row), 1/S at fp32 [512].
// Phase D: att^T = X^T·P^T via mfma (A = Ktb [d][j] contiguous dwordx4,
//          B = P bf16 ds_read_b128). Epilogue via attbuf -> coalesced float4.
#define SLS 520
__global__ __launch_bounds__(256, 4) void attn_kernel(
    const float* __restrict__ Qf, const ushort_t* __restrict__ Xb,
    const ushort_t* __restrict__ Ktb,
    const float* __restrict__ mask, const float* __restrict__ am1v,
    const float* __restrict__ invv, float* __restrict__ ATT)
{
    __shared__ ushort_t qsb[16][72];   // bf16 Q rows, 144B stride (16B aligned)
    __shared__ float SL[16][SLS];      // fp32 scores -> bf16 P alias; [row][512]=1/S
    __shared__ float attbuf[16][68];   // att^T staging

    const int bid = ((blockIdx.x & 7) << 9) + (blockIdx.x >> 3);   // XCD swizzle
    const int bh = bid >> 5;
    const int rg = bid & 31;
    const int b = bh >> 3, h = bh & 7;
    const int tid = threadIdx.x;
    const int w = tid >> 6, lane = tid & 63;
    const int l15 = lane & 15, hi = lane >> 4;

    const float am1 = am1v[bh];
    const float inv = invv[bh];
    const float im1 = inv - 1.f;

    // ---- phase A: load Q rows, convert to bf16 tile ----
    {
        int idx = tid * 4;                       // 0..1023
        int rr = idx >> 6, d4 = idx & 63;
        float4 qv = *(const float4*)&Qf[((size_t)((b << 9) + rg * 16 + rr)) * 512 + (h << 6) + d4];
        ushort4 o;
        o.x = f2b(qv.x); o.y = f2b(qv.y); o.z = f2b(qv.z); o.w = f2b(qv.w);
        *(ushort4*)&qsb[rr][d4] = o;
    }
    __syncthreads();

    // ---- phase B: S^T = K·Q^T via MFMA; wave w covers j in [w*128,(w+1)*128) ----
    {
        const ushort_t* xa = Xb + ((size_t)(b << 9)) * 512 + (h << 6);
        #pragma unroll
        for (int jt = 0; jt < 8; ++jt) {
            const int j0 = w * 128 + jt * 16;
            f32x4 acc = {0.f, 0.f, 0.f, 0.f};
            #pragma unroll
            for (int ks = 0; ks < 2; ++ks) {
                short8 a = *(const short8*)&xa[(size_t)(j0 + l15) * 512 + ks * 32 + hi * 8];
                short8 bf = *(const short8*)&qsb[l15][ks * 32 + hi * 8];
                acc = __builtin_amdgcn_mfma_f32_16x16x32_bf16(a, bf, acc, 0, 0, 0);
            }
            // D: col=l15 -> q, row=hi*4+r -> j-within-tile
            #pragma unroll
            for (int r = 0; r < 4; ++r)
                SL[l15][j0 + hi * 4 + r] = acc[r];
        }
    }
    __syncthreads();

    // ---- phase C: entmax Newton; 2 passes x (two 32-lane groups, 1 row each) ----
    const int l5 = lane & 31, gg = lane >> 5;
    const float NEG = -__builtin_inff();
    const float sc = 0.125f * am1;
    ushort_t* SLu = (ushort_t*)&SL[0][0];        // row q at SLu + q*1040

    #pragma unroll
    for (int pp = 0; pp < 2; ++pp) {
        const int row = w * 4 + pp * 2 + gg;

        float Xs[16];
        #pragma unroll
        for (int e = 0; e < 16; ++e) {
            int j = e * 32 + l5;
            float sv = SL[row][j];
            float mv = (j < 511) ? mask[b * 511 + j] : 0.f;  // last key always masked
            Xs[e] = (mv == 0.f) ? NEG : sv * sc;
        }

        float mx = Xs[0];
        #pragma unroll
        for (int e = 1; e < 16; ++e) mx = fmaxf(mx, Xs[e]);
        mx = rmax32(mx);

        float tau = mx - 1.f;      // f(tau) >= 0 here; f convex decreasing
        for (int it = 0; it < NNEWT; ++it) {
            float s0 = 0.f, s1 = 0.f, g0 = 0.f, g1 = 0.f;
            #pragma unroll
            for (int e = 0; e < 16; e += 2) {
                float za = fmaxf(Xs[e]     - tau, 0.f);
                float zb = fmaxf(Xs[e + 1] - tau, 0.f);
                float da = hw_exp2(im1 * hw_log2(za));   // za^(inv-1)
                float db = hw_exp2(im1 * hw_log2(zb));
                da = (za > 0.f) ? da : 0.f;              // guard im1~0 NaN
                db = (zb > 0.f) ? db : 0.f;
                s0 += da * za; g0 += da;
                s1 += db * zb; g1 += db;
            }
            float S  = rsum32(s0 + s1);
            float Sp = rsum32(g0 + g1);
            tau += (S - 1.f) / (inv * Sp);
        }

        // final eval: unnormalized p -> bf16 in-place (p<=1); 1/S at fp32 [512]
        float s0 = 0.f, s1 = 0.f;
        #pragma unroll
        for (int e = 0; e < 16; e += 2) {
            float za = fmaxf(Xs[e]     - tau, 0.f);
            float zb = fmaxf(Xs[e + 1] - tau, 0.f);
            float pa = hw_exp2(inv * hw_log2(za));       // inv>=1: exp2(-inf)=0
            float pb = hw_exp2(inv * hw_log2(zb));
            SLu[row * 1040 + e * 32 + l5]       = f2b(pa);
            SLu[row * 1040 + (e + 1) * 32 + l5] = f2b(pb);
            s0 += pa; s1 += pb;
        }
        float S = rsum32(s0 + s1);
        if (l5 == 0) SL[row][512] = 1.f / S;
    }
    __syncthreads();

    // ---- phase D: att^T = X^T·P^T via MFMA; wave w owns d-tile [w*16,w*16+16) ----
    {
        const ushort_t* ka = Ktb + (size_t)bh * (64 * 512) + (size_t)(w * 16 + l15) * 512;
        const ushort_t* pb = SLu + l15 * 1040;
        f32x4 acc0 = {0.f, 0.f, 0.f, 0.f};
        f32x4 acc1 = {0.f, 0.f, 0.f, 0.f};
        #pragma unroll
        for (int ks = 0; ks < 16; ks += 2) {
            short8 a0 = *(const short8*)&ka[ks * 32 + hi * 8];
            short8 b0 = *(const short8*)&pb[ks * 32 + hi * 8];
            short8 a1 = *(const short8*)&ka[(ks + 1) * 32 + hi * 8];
            short8 b1 = *(const short8*)&pb[(ks + 1) * 32 + hi * 8];
            acc0 = __builtin_amdgcn_mfma_f32_16x16x32_bf16(a0, b0, acc0, 0, 0, 0);
            acc1 = __builtin_amdgcn_mfma_f32_16x16x32_bf16(a1, b1, acc1, 0, 0, 0);
        }
        // D: col=l15 -> q, row=hi*4+r -> d-within-tile
        #pragma unroll
        for (int r = 0; r < 4; ++r)
            attbuf[l15][w * 16 + hi * 4 + r] = acc0[r] + acc1[r];
    }
    __syncthreads();

    // ---- store: normalize and write coalesced float4 ----
    {
        int idx = tid * 4;                       // 0..1023
        int q = idx >> 6, d4 = idx & 63;
        float rn = SL[q][512];
        float4 o;
        o.x = attbuf[q][d4 + 0] * rn;
        o.y = attbuf[q][d4 + 1] * rn;
        o.z = attbuf[q][d4 + 2] * rn;
        o.w = attbuf[q][d4 + 3] * rn;
        *(float4*)&ATT[((size_t)((b << 9) + rg * 16 + q)) * 512 + (h << 6) + d4] = o;
    }
}

// ---------------- LayerNorm + scatter ----------------
__global__ __launch_bounds__(256) void ln_kernel(const float* __restrict__ Cb,
                                                 const float* __restrict__ g,
                                                 const float* __restrict__ beta,
                                                 float* __restrict__ out)
{
    const int w = threadIdx.x >> 6, lane = threadIdx.x & 63;
    const int row = blockIdx.x * 4 + w;
    const int b = row >> 9, l = row & 511;
    const float* x = Cb + (size_t)row * 512;

    float v[8], s = 0.f;
    #pragma unroll
    for (int k = 0; k < 8; ++k) { v[k] = x[k * 64 + lane]; s += v[k]; }
    s = wsum(s);
    float mu = s * (1.f / 512.f);
    float q = 0.f;
    #pragma unroll
    for (int k = 0; k < 8; ++k) { float d = v[k] - mu; q = fmaf(d, d, q); }
    q = wsum(q);
    float rs = rsqrtf(q * (1.f / 512.f) + 1e-12f);

    float* dst = (l < 511) ? (out + (size_t)(b * 511 + l) * 512)
                           : (out + (size_t)16 * 511 * 512 + (size_t)b * 512);
    #pragma unroll
    for (int k = 0; k < 8; ++k) {
        int d = k * 64 + lane;
        dst[d] = (v[k] - mu) * rs * g[d] + beta[d];
    }
}

// ---------------- launch ----------------
extern "C" void kernel_launch(void* const* d_in, const int* in_sizes, int n_in,
                              void* d_out, int out_size, void* d_ws, size_t ws_size,
                              hipStream_t stream)
{
    const float* X    = (const float*)d_in[0];
    const float* mask = (const float*)d_in[1];
    const float* Wq   = (const float*)d_in[2];
    const float* bq   = (const float*)d_in[3];
    const float* W1   = (const float*)d_in[4];
    const float* b1   = (const float*)d_in[5];
    const float* W2   = (const float*)d_in[6];
    const float* b2   = (const float*)d_in[7];
    const float* lng  = (const float*)d_in[8];
    const float* lnb  = (const float*)d_in[9];
    const float* Wa   = (const float*)d_in[10];
    const float* ba   = (const float*)d_in[11];
    float* out = (float*)d_out;
    float* ws  = (float*)d_ws;

    const size_t NE = (size_t)BB * LL * DD;      // 4194304
    const size_t WN = (size_t)DD * DD;           // 262144
    if (ws_size < (3 * NE + 256) * sizeof(float) + 3 * WN * sizeof(ushort_t)) return;

    // slot 0 (NE fp32): Qb fp32 -> later ATTb/Hhb bf16 pool
    // slot 1 (NE fp32): ATT fp32 (attn out, live as FFN2 residual)
    // slot 2 (NE fp32): Xb bf16 (first half) + Ktb bf16 (second half) -> later Cb fp32
    float* Qb   = ws;
    float* ATT  = ws + NE;
    float* am1v = ws + 3 * NE;
    float* invv = am1v + 128;
    ushort_t* Wqb = (ushort_t*)(am1v + 256);
    ushort_t* W1b = Wqb + WN;
    ushort_t* W2b = W1b + WN;
    ushort_t* Xb  = (ushort_t*)(ws + 2 * NE);
    ushort_t* Ktb = Xb + NE;
    ushort_t* ATTb = (ushort_t*)Qb;        // Qb dead after attn
    ushort_t* Hhb  = (ushort_t*)Qb + NE;
    float* Cb = ws + 2 * NE;               // Xb/Ktb dead after attn

    const int M = BB * LL;       // 8192

    conv_f2b<<<(int)(NE / 1024), 256, 0, stream>>>(X, Xb);
    conv_f2b<<<(int)(WN / 1024), 256, 0, stream>>>(Wq, Wqb);
    gemm_mfma<1, false, false><<<dim3(DD / 64, M / 64), 256, 0, stream>>>(
        Xb, Wqb, bq, nullptr, Qb, M, DD, DD);
    transpose_kt<<<(int)(NE / 256), 256, 0, stream>>>(Xb, Ktb);
    alpha_kernel<<<1, 128, 0, stream>>>(Qb, Wa, ba, am1v, invv);
    attn_kernel<<<BB * HH * LL / 16, 256, 0, stream>>>(Qb, Xb, Ktb, mask, am1v, invv, ATT);
    conv_f2b<<<(int)(NE / 1024), 256, 0, stream>>>(ATT, ATTb);
    conv_f2b<<<(int)(WN / 1024), 256, 0, stream>>>(W1, W1b);
    gemm_mfma<1, false, true><<<dim3(DD / 64, M / 64), 256, 0, stream>>>(
        ATTb, W1b, b1, nullptr, Hhb, M, DD, DD);
    conv_f2b<<<(int)(WN / 1024), 256, 0, stream>>>(W2, W2b);
    gemm_mfma<0, true, false><<<dim3(DD / 64, M / 64), 256, 0, stream>>>(
        Hhb, W2b, b2, ATT, Cb, M, DD, DD);
    ln_kernel<<<M / 4, 256, 0, stream>>>(Cb, lng, lnb, out);
}

// Round 10
// 190.107 us; speedup vs baseline: 2.1245x; 1.2944x over previous
//
#include <hip/hip_runtime.h>
#include <math.h>

#define BB   16
#define LL   512
#define DD   512
#define HH   8
#define HDIM 64
#define NNEWT 8

typedef unsigned short ushort_t;
typedef __attribute__((ext_vector_type(8))) short short8;
typedef __attribute__((ext_vector_type(4))) float f32x4;

// raw single-instruction transcendentals
__device__ __forceinline__ float hw_log2(float x) { return __builtin_amdgcn_logf(x); }
__device__ __forceinline__ float hw_exp2(float x) { return __builtin_amdgcn_exp2f(x); }

__device__ __forceinline__ ushort_t f2b(float f) {
    unsigned u = __builtin_bit_cast(unsigned, f);
    unsigned r = u + 0x7FFFu + ((u >> 16) & 1u);     // RNE
    return (ushort_t)(r >> 16);
}
__device__ __forceinline__ float b2f(ushort_t u) {
    return __builtin_bit_cast(float, ((unsigned)u) << 16);
}

// ---------------- wave-wide reduction (64 lanes) for ln ----------------
__device__ __forceinline__ float wsum(float v) {
    v += __shfl_xor(v, 1);  v += __shfl_xor(v, 2);  v += __shfl_xor(v, 4);
    v += __shfl_xor(v, 8);  v += __shfl_xor(v, 16); v += __shfl_xor(v, 32);
    return v;
}

// ---------------- DPP butterflies (32-lane groups) ----------------
template<int CTRL>
__device__ __forceinline__ float dpp_mov(float v) {
    return __builtin_bit_cast(float, __builtin_amdgcn_update_dpp(
        0, __builtin_bit_cast(int, v), CTRL, 0xf, 0xf, true));
}
__device__ __forceinline__ float rsum32(float v) {
    v += dpp_mov<0xB1>(v);
    v += dpp_mov<0x4E>(v);
    v += dpp_mov<0x141>(v);
    v += dpp_mov<0x140>(v);
    v += __shfl_xor(v, 16);
    return v;
}
__device__ __forceinline__ float rmax32(float v) {
    v = fmaxf(v, dpp_mov<0xB1>(v));
    v = fmaxf(v, dpp_mov<0x4E>(v));
    v = fmaxf(v, dpp_mov<0x141>(v));
    v = fmaxf(v, dpp_mov<0x140>(v));
    v = fmaxf(v, __shfl_xor(v, 16));
    return v;
}

// ---------------- fp32 -> bf16 conversions ----------------
__global__ __launch_bounds__(256) void conv_f2b(const float* __restrict__ in,
                                                ushort_t* __restrict__ out)
{
    int i = (blockIdx.x * 256 + threadIdx.x) * 4;
    float4 v = *(const float4*)&in[i];
    ushort4 o;
    o.x = f2b(v.x); o.y = f2b(v.y); o.z = f2b(v.z); o.w = f2b(v.w);
    *(ushort4*)&out[i] = o;
}

#define WNC 262144
__global__ __launch_bounds__(256) void conv_w3(const float* __restrict__ A,
                                               const float* __restrict__ B,
                                               const float* __restrict__ C,
                                               ushort_t* __restrict__ out)
{
    int i = (blockIdx.x * 256 + threadIdx.x) * 4;
    const float* src; int off;
    if (i < WNC)            { src = A; off = i; }
    else if (i < 2 * WNC)   { src = B; off = i - WNC; }
    else                    { src = C; off = i - 2 * WNC; }
    float4 v = *(const float4*)&src[off];
    ushort4 o;
    o.x = f2b(v.x); o.y = f2b(v.y); o.z = f2b(v.z); o.w = f2b(v.w);
    *(ushort4*)&out[i] = o;
}

// ---------------- bf16 MFMA GEMM: C = act(A @ W^T + bias) [+ bf16 resid] ------
__device__ __forceinline__ void gload16(const void* g, void* l) {
    __builtin_amdgcn_global_load_lds(
        (const __attribute__((address_space(1))) unsigned*)g,
        (__attribute__((address_space(3))) unsigned*)l, 16, 0, 0);
}

template<int ACT, bool RES, bool OBF16>
__global__ __launch_bounds__(256) void gemm_mfma(
    const ushort_t* __restrict__ A, const ushort_t* __restrict__ W,
    const float* __restrict__ bias, const ushort_t* __restrict__ resid,
    void* __restrict__ Cout, int M, int N, int K)
{
    __shared__ ushort_t Asw[64 * 64];
    __shared__ ushort_t Bsw[64 * 64];

    const int tid = threadIdx.x;
    const int w = tid >> 6, lane = tid & 63;
    const int wm = w >> 1, wn = w & 1;
    const int bm = blockIdx.y * 64, bn = blockIdx.x * 64;

    const int l3 = lane >> 3, l7 = lane & 7;
    const int srcg = l7 ^ l3;               // pre-swizzled source granule
    const int l15 = lane & 15, hi = lane >> 4;

    f32x4 acc[2][2] = {};

    for (int kt = 0; kt < K; kt += 64) {
        #pragma unroll
        for (int u = 0; u < 2; ++u) {
            int q = w * 2 + u;
            gload16(&A[(size_t)(bm + q * 8 + l3) * K + kt + srcg * 8], &Asw[q * 512]);
            gload16(&W[(size_t)(bn + q * 8 + l3) * K + kt + srcg * 8], &Bsw[q * 512]);
        }
        __syncthreads();

        #pragma unroll
        for (int kk = 0; kk < 2; ++kk) {
            const int s = (kk * 4 + hi) ^ l7;   // swizzled read granule
            short8 a[2], b[2];
            #pragma unroll
            for (int f = 0; f < 2; ++f) {
                a[f] = *(const short8*)&Asw[(wm * 32 + f * 16 + l15) * 64 + s * 8];
                b[f] = *(const short8*)&Bsw[(wn * 32 + f * 16 + l15) * 64 + s * 8];
            }
            #pragma unroll
            for (int i = 0; i < 2; ++i)
                #pragma unroll
                for (int j = 0; j < 2; ++j)
                    acc[i][j] = __builtin_amdgcn_mfma_f32_16x16x32_bf16(
                        a[i], b[j], acc[i][j], 0, 0, 0);
        }
        __syncthreads();
    }

    #pragma unroll
    for (int i = 0; i < 2; ++i) {
        #pragma unroll
        for (int j = 0; j < 2; ++j) {
            #pragma unroll
            for (int r = 0; r < 4; ++r) {
                const int m = bm + wm * 32 + i * 16 + hi * 4 + r;
                const int n = bn + wn * 32 + j * 16 + l15;
                float v = acc[i][j][r] + bias[n];
                if (ACT == 1) v = fmaxf(v, 0.f);
                if (RES) v += b2f(resid[(size_t)m * N + n]);
                if (OBF16) ((ushort_t*)Cout)[(size_t)m * N + n] = f2b(v);
                else       ((float*)Cout)[(size_t)m * N + n] = v;
            }
        }
    }
}

// ---------------- Ktb[b,h][d][j] = Xb[b,j,h*64+d] (bf16) ----------------
__global__ __launch_bounds__(256) void transpose_kt(const ushort_t* __restrict__ Xb,
                                                    ushort_t* __restrict__ Ktb)
{
    int o = blockIdx.x * 256 + threadIdx.x;
    int j = o & 511;
    int d = (o >> 9) & 63;
    int h = (o >> 15) & 7;
    int b = o >> 18;
    Ktb[o] = Xb[((b << 9) + j) * 512 + h * 64 + d];
}

// ---------------- alpha per (b,h) ----------------
__global__ void alpha_kernel(const float* __restrict__ Q, const float* __restrict__ Wa,
                             const float* __restrict__ ba,
                             float* __restrict__ am1v, float* __restrict__ invv)
{
    int t = threadIdx.x;
    if (t >= BB * HH) return;
    int b = t >> 3, h = t & 7;
    float acc = 0.f;
    #pragma unroll
    for (int d = 0; d < HDIM; ++d)
        acc = fmaf(Q[((b << 9) + 511) * 512 + h * 64 + d], Wa[d], acc);
    acc += ba[0];
    float sig = 1.f / (1.f + expf(-acc));
    float alpha = sig + 1.f;
    const float amin = 1.f + 1e-5f;
    if (alpha < amin) alpha = amin;
    float am1 = alpha - 1.f;
    am1v[t] = am1;
    invv[t] = 1.f / am1;
}

// ---------------- fused attention v9 ----------------
// B: S^T = K·Q^T (MFMA). C: Newton, pair-relabeled lanes (j = u*64+2*l5+{0,1}),
// NNEWT=8, guard-free via im1 clamp; P stored bf16 packed u32. D: att^T = X^T·P^T
// (MFMA). Epilogue writes bf16 ATTb directly (slot1; FFN2 reads bf16 residual).
#define SLS 520
__global__ __launch_bounds__(256, 4) void attn_kernel(
    const float* __restrict__ Qf, const ushort_t* __restrict__ Xb,
    const ushort_t* __restrict__ Ktb,
    const float* __restrict__ mask, const float* __restrict__ am1v,
    const float* __restrict__ invv, ushort_t* __restrict__ ATTb)
{
    __shared__ ushort_t qsb[16][72];   // bf16 Q rows
    __shared__ float SL[16][SLS];      // fp32 scores -> bf16 P alias; [row][512]=1/S
    __shared__ float attbuf[16][68];   // att^T staging

    const int bid = ((blockIdx.x & 7) << 9) + (blockIdx.x >> 3);   // XCD swizzle
    const int bh = bid >> 5;
    const int rg = bid & 31;
    const int b = bh >> 3, h = bh & 7;
    const int tid = threadIdx.x;
    const int w = tid >> 6, lane = tid & 63;
    const int l15 = lane & 15, hi = lane >> 4;

    const float am1 = am1v[bh];
    const float inv = invv[bh];
    const float im1c = fmaxf(inv - 1.f, 1e-30f);   // >0 so im1c*log2(0) = -inf -> 0

    // ---- phase A: load Q rows, convert to bf16 tile ----
    {
        int idx = tid * 4;
        int rr = idx >> 6, d4 = idx & 63;
        float4 qv = *(const float4*)&Qf[((size_t)((b << 9) + rg * 16 + rr)) * 512 + (h << 6) + d4];
        ushort4 o;
        o.x = f2b(qv.x); o.y = f2b(qv.y); o.z = f2b(qv.z); o.w = f2b(qv.w);
        *(ushort4*)&qsb[rr][d4] = o;
    }
    __syncthreads();

    // ---- phase B: S^T = K·Q^T via MFMA; wave w covers j in [w*128,(w+1)*128) ----
    {
        const ushort_t* xa = Xb + ((size_t)(b << 9)) * 512 + (h << 6);
        #pragma unroll
        for (int jt = 0; jt < 8; ++jt) {
            const int j0 = w * 128 + jt * 16;
            f32x4 acc = {0.f, 0.f, 0.f, 0.f};
            #pragma unroll
            for (int ks = 0; ks < 2; ++ks) {
                short8 a = *(const short8*)&xa[(size_t)(j0 + l15) * 512 + ks * 32 + hi * 8];
                short8 bf = *(const short8*)&qsb[l15][ks * 32 + hi * 8];
                acc = __builtin_amdgcn_mfma_f32_16x16x32_bf16(a, bf, acc, 0, 0, 0);
            }
            #pragma unroll
            for (int r = 0; r < 4; ++r)
                SL[l15][j0 + hi * 4 + r] = acc[r];
        }
    }
    __syncthreads();

    // ---- phase C: entmax Newton; 2 passes x (two 32-lane groups, 1 row each) ----
    const int l5 = lane & 31, gg = lane >> 5;
    const float NEG = -__builtin_inff();
    const float sc = 0.125f * am1;
    ushort_t* SLu = (ushort_t*)&SL[0][0];        // row q at SLu + q*1040

    #pragma unroll
    for (int pp = 0; pp < 2; ++pp) {
        const int row = w * 4 + pp * 2 + gg;

        // lane owns pairs j = u*64 + 2*l5 + {0,1}
        float Xs[16];
        #pragma unroll
        for (int u = 0; u < 8; ++u) {
            int j0 = u * 64 + 2 * l5;
            float2 sv = *(const float2*)&SL[row][j0];
            float mv0 = mask[b * 511 + j0];                      // j0 <= 510
            float mv1 = (j0 + 1 < 511) ? mask[b * 511 + j0 + 1] : 0.f;
            Xs[2*u]   = (mv0 == 0.f) ? NEG : sv.x * sc;
            Xs[2*u+1] = (mv1 == 0.f) ? NEG : sv.y * sc;
        }

        float mx = Xs[0];
        #pragma unroll
        for (int e = 1; e < 16; ++e) mx = fmaxf(mx, Xs[e]);
        mx = rmax32(mx);

        float tau = mx - 1.f;      // f(tau) >= 0 here; f convex decreasing
        for (int it = 0; it < NNEWT; ++it) {
            float s0 = 0.f, s1 = 0.f, g0 = 0.f, g1 = 0.f;
            #pragma unroll
            for (int e = 0; e < 16; e += 2) {
                float za = fmaxf(Xs[e]     - tau, 0.f);
                float zb = fmaxf(Xs[e + 1] - tau, 0.f);
                float da = hw_exp2(im1c * hw_log2(za));   // za^(inv-1); 0 at za=0
                float db = hw_exp2(im1c * hw_log2(zb));
                s0 += da * za; g0 += da;
                s1 += db * zb; g1 += db;
            }
            float S  = rsum32(s0 + s1);
            float Sp = rsum32(g0 + g1);
            tau += (S - 1.f) / (inv * Sp);
        }

        // final eval: unnormalized p -> bf16 packed u32; 1/S at fp32 [512]
        float s0 = 0.f, s1 = 0.f;
        #pragma unroll
        for (int u = 0; u < 8; ++u) {
            int j0 = u * 64 + 2 * l5;
            float za = fmaxf(Xs[2*u]   - tau, 0.f);
            float zb = fmaxf(Xs[2*u+1] - tau, 0.f);
            float pa = hw_exp2(inv * hw_log2(za));       // inv>=1: exp2(-inf)=0
            float pb = hw_exp2(inv * hw_log2(zb));
            unsigned pk = (unsigned)f2b(pa) | ((unsigned)f2b(pb) << 16);
            *(unsigned*)&SLu[row * 1040 + j0] = pk;
            s0 += pa; s1 += pb;
        }
        float S = rsum32(s0 + s1);
        if (l5 == 0) SL[row][512] = 1.f / S;
    }
    __syncthreads();

    // ---- phase D: att^T = X^T·P^T via MFMA; wave w owns d-tile [w*16,w*16+16) ----
    {
        const ushort_t* ka = Ktb + (size_t)bh * (64 * 512) + (size_t)(w * 16 + l15) * 512;
        const ushort_t* pb = SLu + l15 * 1040;
        f32x4 acc0 = {0.f, 0.f, 0.f, 0.f};
        f32x4 acc1 = {0.f, 0.f, 0.f, 0.f};
        #pragma unroll
        for (int ks = 0; ks < 16; ks += 2) {
            short8 a0 = *(const short8*)&ka[ks * 32 + hi * 8];
            short8 b0 = *(const short8*)&pb[ks * 32 + hi * 8];
            short8 a1 = *(const short8*)&ka[(ks + 1) * 32 + hi * 8];
            short8 b1 = *(const short8*)&pb[(ks + 1) * 32 + hi * 8];
            acc0 = __builtin_amdgcn_mfma_f32_16x16x32_bf16(a0, b0, acc0, 0, 0, 0);
            acc1 = __builtin_amdgcn_mfma_f32_16x16x32_bf16(a1, b1, acc1, 0, 0, 0);
        }
        #pragma unroll
        for (int r = 0; r < 4; ++r)
            attbuf[l15][w * 16 + hi * 4 + r] = acc0[r] + acc1[r];
    }
    __syncthreads();

    // ---- store: normalize, write bf16 ATTb coalesced (ushort4 = 8B/lane) ----
    {
        int idx = tid * 4;
        int q = idx >> 6, d4 = idx & 63;
        float rn = SL[q][512];
        ushort4 o;
        o.x = f2b(attbuf[q][d4 + 0] * rn);
        o.y = f2b(attbuf[q][d4 + 1] * rn);
        o.z = f2b(attbuf[q][d4 + 2] * rn);
        o.w = f2b(attbuf[q][d4 + 3] * rn);
        *(ushort4*)&ATTb[((size_t)((b << 9) + rg * 16 + q)) * 512 + (h << 6) + d4] = o;
    }
}

// ---------------- LayerNorm + scatter ----------------
__global__ __launch_bounds__(256) void ln_kernel(const float* __restrict__ Cb,
                                                 const float* __restrict__ g,
                                                 const float* __restrict__ beta,
                                                 float* __restrict__ out)
{
    const int w = threadIdx.x >> 6, lane = threadIdx.x & 63;
    const int row = blockIdx.x * 4 + w;
    const int b = row >> 9, l = row & 511;
    const float* x = Cb + (size_t)row * 512;

    float v[8], s = 0.f;
    #pragma unroll
    for (int k = 0; k < 8; ++k) { v[k] = x[k * 64 + lane]; s += v[k]; }
    s = wsum(s);
    float mu = s * (1.f / 512.f);
    float q = 0.f;
    #pragma unroll
    for (int k = 0; k < 8; ++k) { float d = v[k] - mu; q = fmaf(d, d, q); }
    q = wsum(q);
    float rs = rsqrtf(q * (1.f / 512.f) + 1e-12f);

    float* dst = (l < 511) ? (out + (size_t)(b * 511 + l) * 512)
                           : (out + (size_t)16 * 511 * 512 + (size_t)b * 512);
    #pragma unroll
    for (int k = 0; k < 8; ++k) {
        int d = k * 64 + lane;
        dst[d] = (v[k] - mu) * rs * g[d] + beta[d];
    }
}

// ---------------- launch ----------------
extern "C" void kernel_launch(void* const* d_in, const int* in_sizes, int n_in,
                              void* d_out, int out_size, void* d_ws, size_t ws_size,
                              hipStream_t stream)
{
    const float* X    = (const float*)d_in[0];
    const float* mask = (const float*)d_in[1];
    const float* Wq   = (const float*)d_in[2];
    const float* bq   = (const float*)d_in[3];
    const float* W1   = (const float*)d_in[4];
    const float* b1   = (const float*)d_in[5];
    const float* W2   = (const float*)d_in[6];
    const float* b2   = (const float*)d_in[7];
    const float* lng  = (const float*)d_in[8];
    const float* lnb  = (const float*)d_in[9];
    const float* Wa   = (const float*)d_in[10];
    const float* ba   = (const float*)d_in[11];
    float* out = (float*)d_out;
    float* ws  = (float*)d_ws;

    const size_t NE = (size_t)BB * LL * DD;      // 4194304
    const size_t WN = (size_t)DD * DD;           // 262144
    if (ws_size < (3 * NE + 256) * sizeof(float) + 3 * WN * sizeof(ushort_t)) return;

    // slot 0 (NE f32): Qb fp32; after attn: Hhb bf16 (2nd half)
    // slot 1 (NE f32): ATTb bf16 (1st half) — attn out, FFN1 A, FFN2 residual
    // slot 2 (NE f32): Xb bf16 + Ktb bf16; after attn: Cb fp32
    float* Qb   = ws;
    float* am1v = ws + 3 * NE;
    float* invv = am1v + 128;
    ushort_t* Wqb = (ushort_t*)(am1v + 256);
    ushort_t* W1b = Wqb + WN;
    ushort_t* W2b = W1b + WN;
    ushort_t* ATTb = (ushort_t*)(ws + NE);
    ushort_t* Xb  = (ushort_t*)(ws + 2 * NE);
    ushort_t* Ktb = Xb + NE;
    ushort_t* Hhb = (ushort_t*)Qb + NE;    // Qb dead after attn
    float* Cb = ws + 2 * NE;               // Xb/Ktb dead after attn

    const int M = BB * LL;       // 8192

    conv_f2b<<<(int)(NE / 1024), 256, 0, stream>>>(X, Xb);
    conv_w3<<<(int)(3 * WN / 1024), 256, 0, stream>>>(Wq, W1, W2, Wqb);
    gemm_mfma<1, false, false><<<dim3(DD / 64, M / 64), 256, 0, stream>>>(
        Xb, Wqb, bq, nullptr, Qb, M, DD, DD);
    transpose_kt<<<(int)(NE / 256), 256, 0, stream>>>(Xb, Ktb);
    alpha_kernel<<<1, 128, 0, stream>>>(Qb, Wa, ba, am1v, invv);
    attn_kernel<<<BB * HH * LL / 16, 256, 0, stream>>>(Qb, Xb, Ktb, mask, am1v, invv, ATTb);
    gemm_mfma<1, false, true><<<dim3(DD / 64, M / 64), 256, 0, stream>>>(
        ATTb, W1b, b1, nullptr, Hhb, M, DD, DD);
    gemm_mfma<0, true, false><<<dim3(DD / 64, M / 64), 256, 0, stream>>>(
        Hhb, W2b, b2, ATTb, Cb, M, DD, DD);
    ln_kernel<<<M / 4, 256, 0, stream>>>(Cb, lng, lnb, out);
}

// Round 11
// 175.824 us; speedup vs baseline: 2.2971x; 1.0812x over previous
//
#include <hip/hip_runtime.h>
#include <math.h>

#define BB   16
#define LL   512
#define DD   512
#define HH   8
#define HDIM 64
#define NNEWT 8

typedef unsigned short ushort_t;
typedef __attribute__((ext_vector_type(8))) short short8;
typedef __attribute__((ext_vector_type(4))) float f32x4;

// raw single-instruction transcendentals
__device__ __forceinline__ float hw_log2(float x) { return __builtin_amdgcn_logf(x); }
__device__ __forceinline__ float hw_exp2(float x) { return __builtin_amdgcn_exp2f(x); }

__device__ __forceinline__ ushort_t f2b(float f) {
    unsigned u = __builtin_bit_cast(unsigned, f);
    unsigned r = u + 0x7FFFu + ((u >> 16) & 1u);     // RNE
    return (ushort_t)(r >> 16);
}
__device__ __forceinline__ float b2f(ushort_t u) {
    return __builtin_bit_cast(float, ((unsigned)u) << 16);
}

// ---------------- wave-wide reduction (64 lanes) for ln ----------------
__device__ __forceinline__ float wsum(float v) {
    v += __shfl_xor(v, 1);  v += __shfl_xor(v, 2);  v += __shfl_xor(v, 4);
    v += __shfl_xor(v, 8);  v += __shfl_xor(v, 16); v += __shfl_xor(v, 32);
    return v;
}

// ---------------- DPP butterflies (32-lane groups) ----------------
template<int CTRL>
__device__ __forceinline__ float dpp_mov(float v) {
    return __builtin_bit_cast(float, __builtin_amdgcn_update_dpp(
        0, __builtin_bit_cast(int, v), CTRL, 0xf, 0xf, true));
}
__device__ __forceinline__ float rsum32(float v) {
    v += dpp_mov<0xB1>(v);
    v += dpp_mov<0x4E>(v);
    v += dpp_mov<0x141>(v);
    v += dpp_mov<0x140>(v);
    v += __shfl_xor(v, 16);
    return v;
}
__device__ __forceinline__ float rmax32(float v) {
    v = fmaxf(v, dpp_mov<0xB1>(v));
    v = fmaxf(v, dpp_mov<0x4E>(v));
    v = fmaxf(v, dpp_mov<0x141>(v));
    v = fmaxf(v, dpp_mov<0x140>(v));
    v = fmaxf(v, __shfl_xor(v, 16));
    return v;
}

// ---------------- all fp32 -> bf16 conversions in one kernel ----------------
#define NEC 4194304
#define WNC 262144
__global__ __launch_bounds__(256) void conv_all(
    const float* __restrict__ X, const float* __restrict__ Wq,
    const float* __restrict__ W1, const float* __restrict__ W2,
    ushort_t* __restrict__ Xb, ushort_t* __restrict__ Wb)
{
    int i = (blockIdx.x * 256 + threadIdx.x) * 4;
    const float* src; ushort_t* dst; int off, doff;
    if (i < NEC) { src = X; dst = Xb; off = i; doff = i; }
    else {
        int k = i - NEC;
        dst = Wb; doff = k;
        if (k < WNC)          { src = Wq; off = k; }
        else if (k < 2 * WNC) { src = W1; off = k - WNC; }
        else                  { src = W2; off = k - 2 * WNC; }
    }
    float4 v = *(const float4*)&src[off];
    ushort4 o;
    o.x = f2b(v.x); o.y = f2b(v.y); o.z = f2b(v.z); o.w = f2b(v.w);
    *(ushort4*)&dst[doff] = o;
}

// ---------------- bf16 MFMA GEMM: C = act(A @ W^T + bias) [+ bf16 resid] ------
__device__ __forceinline__ void gload16(const void* g, void* l) {
    __builtin_amdgcn_global_load_lds(
        (const __attribute__((address_space(1))) unsigned*)g,
        (__attribute__((address_space(3))) unsigned*)l, 16, 0, 0);
}

template<int ACT, bool RES, bool OBF16>
__global__ __launch_bounds__(256) void gemm_mfma(
    const ushort_t* __restrict__ A, const ushort_t* __restrict__ W,
    const float* __restrict__ bias, const ushort_t* __restrict__ resid,
    void* __restrict__ Cout, int M, int N, int K)
{
    __shared__ ushort_t Asw[64 * 64];
    __shared__ ushort_t Bsw[64 * 64];

    const int tid = threadIdx.x;
    const int w = tid >> 6, lane = tid & 63;
    const int wm = w >> 1, wn = w & 1;
    const int bm = blockIdx.y * 64, bn = blockIdx.x * 64;

    const int l3 = lane >> 3, l7 = lane & 7;
    const int srcg = l7 ^ l3;               // pre-swizzled source granule
    const int l15 = lane & 15, hi = lane >> 4;

    f32x4 acc[2][2] = {};

    for (int kt = 0; kt < K; kt += 64) {
        #pragma unroll
        for (int u = 0; u < 2; ++u) {
            int q = w * 2 + u;
            gload16(&A[(size_t)(bm + q * 8 + l3) * K + kt + srcg * 8], &Asw[q * 512]);
            gload16(&W[(size_t)(bn + q * 8 + l3) * K + kt + srcg * 8], &Bsw[q * 512]);
        }
        __syncthreads();

        #pragma unroll
        for (int kk = 0; kk < 2; ++kk) {
            const int s = (kk * 4 + hi) ^ l7;   // swizzled read granule
            short8 a[2], b[2];
            #pragma unroll
            for (int f = 0; f < 2; ++f) {
                a[f] = *(const short8*)&Asw[(wm * 32 + f * 16 + l15) * 64 + s * 8];
                b[f] = *(const short8*)&Bsw[(wn * 32 + f * 16 + l15) * 64 + s * 8];
            }
            #pragma unroll
            for (int i = 0; i < 2; ++i)
                #pragma unroll
                for (int j = 0; j < 2; ++j)
                    acc[i][j] = __builtin_amdgcn_mfma_f32_16x16x32_bf16(
                        a[i], b[j], acc[i][j], 0, 0, 0);
        }
        __syncthreads();
    }

    #pragma unroll
    for (int i = 0; i < 2; ++i) {
        #pragma unroll
        for (int j = 0; j < 2; ++j) {
            #pragma unroll
            for (int r = 0; r < 4; ++r) {
                const int m = bm + wm * 32 + i * 16 + hi * 4 + r;
                const int n = bn + wn * 32 + j * 16 + l15;
                float v = acc[i][j][r] + bias[n];
                if (ACT == 1) v = fmaxf(v, 0.f);
                if (RES) v += b2f(resid[(size_t)m * N + n]);
                if (OBF16) ((ushort_t*)Cout)[(size_t)m * N + n] = f2b(v);
                else       ((float*)Cout)[(size_t)m * N + n] = v;
            }
        }
    }
}

// ---------------- Ktb[b,h][d][j] = Xb[b,j,h*64+d] (bf16) ----------------
__global__ __launch_bounds__(256) void transpose_kt(const ushort_t* __restrict__ Xb,
                                                    ushort_t* __restrict__ Ktb)
{
    int o = blockIdx.x * 256 + threadIdx.x;
    int j = o & 511;
    int d = (o >> 9) & 63;
    int h = (o >> 15) & 7;
    int b = o >> 18;
    Ktb[o] = Xb[((b << 9) + j) * 512 + h * 64 + d];
}

// ---------------- alpha per (b,h), bf16 q ----------------
__global__ void alpha_kernel(const ushort_t* __restrict__ Qb, const float* __restrict__ Wa,
                             const float* __restrict__ ba,
                             float* __restrict__ am1v, float* __restrict__ invv)
{
    int t = threadIdx.x;
    if (t >= BB * HH) return;
    int b = t >> 3, h = t & 7;
    float acc = 0.f;
    #pragma unroll
    for (int d = 0; d < HDIM; ++d)
        acc = fmaf(b2f(Qb[((b << 9) + 511) * 512 + h * 64 + d]), Wa[d], acc);
    acc += ba[0];
    float sig = 1.f / (1.f + expf(-acc));
    float alpha = sig + 1.f;
    const float amin = 1.f + 1e-5f;
    if (alpha < amin) alpha = amin;
    float am1 = alpha - 1.f;
    am1v[t] = am1;
    invv[t] = 1.f / am1;
}

// ---------------- fused attention v10 ----------------
// A: bf16 Q tile load + mask staged into attbuf alias. B: S^T = K·Q^T (MFMA)
// with mask+scale pre-applied at D-write (mask read = LDS broadcast).
// C: Newton, za via [0,1] clamp (exact: tau >= mx-1 -> z <= 1), no mask work.
// D: att^T = X^T·P^T (MFMA), bf16 epilogue.
#define SLS 520
__global__ __launch_bounds__(256, 4) void attn_kernel(
    const ushort_t* __restrict__ Qb, const ushort_t* __restrict__ Xb,
    const ushort_t* __restrict__ Ktb,
    const float* __restrict__ mask, const float* __restrict__ am1v,
    const float* __restrict__ invv, ushort_t* __restrict__ ATTb)
{
    __shared__ ushort_t qsb[16][72];   // bf16 Q rows
    __shared__ float SL[16][SLS];      // masked scaled scores -> bf16 P; [row][512]=1/S
    __shared__ float attbuf[16][68];   // mask[512] (phases A-C), att^T staging (D)

    const int bid = ((blockIdx.x & 7) << 9) + (blockIdx.x >> 3);   // XCD swizzle
    const int bh = bid >> 5;
    const int rg = bid & 31;
    const int b = bh >> 3, h = bh & 7;
    const int tid = threadIdx.x;
    const int w = tid >> 6, lane = tid & 63;
    const int l15 = lane & 15, hi = lane >> 4;

    const float am1 = am1v[bh];
    const float inv = invv[bh];
    const float im1c = fmaxf(inv - 1.f, 1e-30f);   // >0 so im1c*log2(0) = -inf -> 0
    const float NEG = -__builtin_inff();
    const float sc = 0.125f * am1;
    float* mlds = &attbuf[0][0];

    // ---- phase A: bf16 Q tile + mask -> LDS ----
    {
        int idx = tid * 4;
        int rr = idx >> 6, d4 = idx & 63;
        *(ushort4*)&qsb[rr][d4] =
            *(const ushort4*)&Qb[((size_t)((b << 9) + rg * 16 + rr)) * 512 + (h << 6) + d4];
    }
    #pragma unroll
    for (int u = 0; u < 2; ++u) {
        int j = tid + u * 256;
        mlds[j] = (j < 511) ? mask[b * 511 + j] : 0.f;   // last key always masked
    }
    __syncthreads();

    // ---- phase B: S^T = K·Q^T via MFMA; mask+scale applied at write ----
    {
        const ushort_t* xa = Xb + ((size_t)(b << 9)) * 512 + (h << 6);
        #pragma unroll
        for (int jt = 0; jt < 8; ++jt) {
            const int j0 = w * 128 + jt * 16;
            f32x4 acc = {0.f, 0.f, 0.f, 0.f};
            #pragma unroll
            for (int ks = 0; ks < 2; ++ks) {
                short8 a = *(const short8*)&xa[(size_t)(j0 + l15) * 512 + ks * 32 + hi * 8];
                short8 bf = *(const short8*)&qsb[l15][ks * 32 + hi * 8];
                acc = __builtin_amdgcn_mfma_f32_16x16x32_bf16(a, bf, acc, 0, 0, 0);
            }
            #pragma unroll
            for (int r = 0; r < 4; ++r) {
                int j = j0 + hi * 4 + r;
                float mv = mlds[j];                      // 16-lane broadcast
                SL[l15][j] = (mv == 0.f) ? NEG : acc[r] * sc;
            }
        }
    }
    __syncthreads();

    // ---- phase C: entmax Newton; 2 passes x (two 32-lane groups, 1 row each) ----
    const int l5 = lane & 31, gg = lane >> 5;
    ushort_t* SLu = (ushort_t*)&SL[0][0];        // row q at SLu + q*1040

    #pragma unroll
    for (int pp = 0; pp < 2; ++pp) {
        const int row = w * 4 + pp * 2 + gg;

        // lane owns pairs j = u*64 + 2*l5 + {0,1}; SL already masked+scaled
        float Xs[16];
        #pragma unroll
        for (int u = 0; u < 8; ++u) {
            float2 sv = *(const float2*)&SL[row][u * 64 + 2 * l5];
            Xs[2*u] = sv.x; Xs[2*u+1] = sv.y;
        }

        float mx = Xs[0];
        #pragma unroll
        for (int e = 1; e < 16; ++e) mx = fmaxf(mx, Xs[e]);
        mx = rmax32(mx);

        float tau = mx - 1.f;      // f(tau) >= 0 here; f convex decreasing
        for (int it = 0; it < NNEWT; ++it) {
            float s0 = 0.f, s1 = 0.f, g0 = 0.f, g1 = 0.f;
            #pragma unroll
            for (int e = 0; e < 16; e += 2) {
                // z <= 1 provably (tau >= mx-1), so [0,1] clamp == max(z,0)
                float za = fminf(fmaxf(Xs[e]     - tau, 0.f), 1.f);
                float zb = fminf(fmaxf(Xs[e + 1] - tau, 0.f), 1.f);
                float da = hw_exp2(im1c * hw_log2(za));   // za^(inv-1); 0 at za=0
                float db = hw_exp2(im1c * hw_log2(zb));
                s0 += da * za; g0 += da;
                s1 += db * zb; g1 += db;
            }
            float S  = rsum32(s0 + s1);
            float Sp = rsum32(g0 + g1);
            tau += (S - 1.f) / (inv * Sp);
        }

        // final eval: unnormalized p -> bf16 packed u32; 1/S at fp32 [512]
        float s0 = 0.f, s1 = 0.f;
        #pragma unroll
        for (int u = 0; u < 8; ++u) {
            int j0 = u * 64 + 2 * l5;
            float za = fminf(fmaxf(Xs[2*u]   - tau, 0.f), 1.f);
            float zb = fminf(fmaxf(Xs[2*u+1] - tau, 0.f), 1.f);
            float pa = hw_exp2(inv * hw_log2(za));       // inv>=1: exp2(-inf)=0
            float pb = hw_exp2(inv * hw_log2(zb));
            unsigned pk = (unsigned)f2b(pa) | ((unsigned)f2b(pb) << 16);
            *(unsigned*)&SLu[row * 1040 + j0] = pk;
            s0 += pa; s1 += pb;
        }
        float S = rsum32(s0 + s1);
        if (l5 == 0) SL[row][512] = 1.f / S;
    }
    __syncthreads();   // also separates mask use (attbuf) from phase D writes

    // ---- phase D: att^T = X^T·P^T via MFMA; wave w owns d-tile [w*16,w*16+16) ----
    {
        const ushort_t* ka = Ktb + (size_t)bh * (64 * 512) + (size_t)(w * 16 + l15) * 512;
        const ushort_t* pb = SLu + l15 * 1040;
        f32x4 acc0 = {0.f, 0.f, 0.f, 0.f};
        f32x4 acc1 = {0.f, 0.f, 0.f, 0.f};
        #pragma unroll
        for (int ks = 0; ks < 16; ks += 2) {
            short8 a0 = *(const short8*)&ka[ks * 32 + hi * 8];
            short8 b0 = *(const short8*)&pb[ks * 32 + hi * 8];
            short8 a1 = *(const short8*)&ka[(ks + 1) * 32 + hi * 8];
            short8 b1 = *(const short8*)&pb[(ks + 1) * 32 + hi * 8];
            acc0 = __builtin_amdgcn_mfma_f32_16x16x32_bf16(a0, b0, acc0, 0, 0, 0);
            acc1 = __builtin_amdgcn_mfma_f32_16x16x32_bf16(a1, b1, acc1, 0, 0, 0);
        }
        #pragma unroll
        for (int r = 0; r < 4; ++r)
            attbuf[l15][w * 16 + hi * 4 + r] = acc0[r] + acc1[r];
    }
    __syncthreads();

    // ---- store: normalize, write bf16 ATTb coalesced (ushort4 = 8B/lane) ----
    {
        int idx = tid * 4;
        int q = idx >> 6, d4 = idx & 63;
        float rn = SL[q][512];
        ushort4 o;
        o.x = f2b(attbuf[q][d4 + 0] * rn);
        o.y = f2b(attbuf[q][d4 + 1] * rn);
        o.z = f2b(attbuf[q][d4 + 2] * rn);
        o.w = f2b(attbuf[q][d4 + 3] * rn);
        *(ushort4*)&ATTb[((size_t)((b << 9) + rg * 16 + q)) * 512 + (h << 6) + d4] = o;
    }
}

// ---------------- LayerNorm + scatter ----------------
__global__ __launch_bounds__(256) void ln_kernel(const float* __restrict__ Cb,
                                                 const float* __restrict__ g,
                                                 const float* __restrict__ beta,
                                                 float* __restrict__ out)
{
    const int w = threadIdx.x >> 6, lane = threadIdx.x & 63;
    const int row = blockIdx.x * 4 + w;
    const int b = row >> 9, l = row & 511;
    const float* x = Cb + (size_t)row * 512;

    float v[8], s = 0.f;
    #pragma unroll
    for (int k = 0; k < 8; ++k) { v[k] = x[k * 64 + lane]; s += v[k]; }
    s = wsum(s);
    float mu = s * (1.f / 512.f);
    float q = 0.f;
    #pragma unroll
    for (int k = 0; k < 8; ++k) { float d = v[k] - mu; q = fmaf(d, d, q); }
    q = wsum(q);
    float rs = rsqrtf(q * (1.f / 512.f) + 1e-12f);

    float* dst = (l < 511) ? (out + (size_t)(b * 511 + l) * 512)
                           : (out + (size_t)16 * 511 * 512 + (size_t)b * 512);
    #pragma unroll
    for (int k = 0; k < 8; ++k) {
        int d = k * 64 + lane;
        dst[d] = (v[k] - mu) * rs * g[d] + beta[d];
    }
}

// ---------------- launch ----------------
extern "C" void kernel_launch(void* const* d_in, const int* in_sizes, int n_in,
                              void* d_out, int out_size, void* d_ws, size_t ws_size,
                              hipStream_t stream)
{
    const float* X    = (const float*)d_in[0];
    const float* mask = (const float*)d_in[1];
    const float* Wq   = (const float*)d_in[2];
    const float* bq   = (const float*)d_in[3];
    const float* W1   = (const float*)d_in[4];
    const float* b1   = (const float*)d_in[5];
    const float* W2   = (const float*)d_in[6];
    const float* b2   = (const float*)d_in[7];
    const float* lng  = (const float*)d_in[8];
    const float* lnb  = (const float*)d_in[9];
    const float* Wa   = (const float*)d_in[10];
    const float* ba   = (const float*)d_in[11];
    float* out = (float*)d_out;
    float* ws  = (float*)d_ws;

    const size_t NE = (size_t)BB * LL * DD;      // 4194304
    const size_t WN = (size_t)DD * DD;           // 262144
    if (ws_size < (3 * NE + 256) * sizeof(float) + 3 * WN * sizeof(ushort_t)) return;

    // slot 0 (NE f32 = 2NE u16): Qb bf16 (1st half) + Hhb bf16 (2nd half)
    // slot 1 (NE f32): ATTb bf16 (1st half) — attn out, FFN1 A, FFN2 residual
    // slot 2 (NE f32): Xb bf16 + Ktb bf16; after attn: Cb fp32
    float* am1v = ws + 3 * NE;
    float* invv = am1v + 128;
    ushort_t* Wqb = (ushort_t*)(am1v + 256);
    ushort_t* W1b = Wqb + WN;
    ushort_t* W2b = W1b + WN;
    ushort_t* Qbb = (ushort_t*)ws;
    ushort_t* Hhb = Qbb + NE;
    ushort_t* ATTb = (ushort_t*)(ws + NE);
    ushort_t* Xb  = (ushort_t*)(ws + 2 * NE);
    ushort_t* Ktb = Xb + NE;
    float* Cb = ws + 2 * NE;               // Xb/Ktb dead after attn

    const int M = BB * LL;       // 8192

    conv_all<<<(int)((NE + 3 * WN) / 1024), 256, 0, stream>>>(X, Wq, W1, W2, Xb, Wqb);
    gemm_mfma<1, false, true><<<dim3(DD / 64, M / 64), 256, 0, stream>>>(
        Xb, Wqb, bq, nullptr, Qbb, M, DD, DD);
    transpose_kt<<<(int)(NE / 256), 256, 0, stream>>>(Xb, Ktb);
    alpha_kernel<<<1, 128, 0, stream>>>(Qbb, Wa, ba, am1v, invv);
    attn_kernel<<<BB * HH * LL / 16, 256, 0, stream>>>(Qbb, Xb, Ktb, mask, am1v, invv, ATTb);
    gemm_mfma<1, false, true><<<dim3(DD / 64, M / 64), 256, 0, stream>>>(
        ATTb, W1b, b1, nullptr, Hhb, M, DD, DD);
    gemm_mfma<0, true, false><<<dim3(DD / 64, M / 64), 256, 0, stream>>>(
        Hhb, W2b, b2, ATTb, Cb, M, DD, DD);
    ln_kernel<<<M / 4, 256, 0, stream>>>(Cb, lng, lnb, out);
}

// Round 12
// 149.494 us; speedup vs baseline: 2.7017x; 1.1761x over previous
//
#include <hip/hip_runtime.h>
#include <math.h>

#define BB   16
#define LL   512
#define DD   512
#define HH   8
#define HDIM 64
#define NNEWT 6

typedef unsigned short ushort_t;
typedef __attribute__((ext_vector_type(8))) short short8;
typedef __attribute__((ext_vector_type(4))) float f32x4;

// raw single-instruction transcendentals
__device__ __forceinline__ float hw_log2(float x) { return __builtin_amdgcn_logf(x); }
__device__ __forceinline__ float hw_exp2(float x) { return __builtin_amdgcn_exp2f(x); }
__device__ __forceinline__ float hw_rcp(float x)  { return __builtin_amdgcn_rcpf(x); }

__device__ __forceinline__ ushort_t f2b(float f) {
    unsigned u = __builtin_bit_cast(unsigned, f);
    unsigned r = u + 0x7FFFu + ((u >> 16) & 1u);     // RNE
    return (ushort_t)(r >> 16);
}
__device__ __forceinline__ float b2f(ushort_t u) {
    return __builtin_bit_cast(float, ((unsigned)u) << 16);
}

// ---------------- wave-wide reduction (64 lanes) for ln ----------------
__device__ __forceinline__ float wsum(float v) {
    v += __shfl_xor(v, 1);  v += __shfl_xor(v, 2);  v += __shfl_xor(v, 4);
    v += __shfl_xor(v, 8);  v += __shfl_xor(v, 16); v += __shfl_xor(v, 32);
    return v;
}

// ---------------- DPP butterflies (32-lane groups) ----------------
template<int CTRL>
__device__ __forceinline__ float dpp_mov(float v) {
    return __builtin_bit_cast(float, __builtin_amdgcn_update_dpp(
        0, __builtin_bit_cast(int, v), CTRL, 0xf, 0xf, true));
}
__device__ __forceinline__ float rsum32(float v) {
    v += dpp_mov<0xB1>(v);
    v += dpp_mov<0x4E>(v);
    v += dpp_mov<0x141>(v);
    v += dpp_mov<0x140>(v);
    v += __shfl_xor(v, 16);
    return v;
}
__device__ __forceinline__ float rmax32(float v) {
    v = fmaxf(v, dpp_mov<0xB1>(v));
    v = fmaxf(v, dpp_mov<0x4E>(v));
    v = fmaxf(v, dpp_mov<0x141>(v));
    v = fmaxf(v, dpp_mov<0x140>(v));
    v = fmaxf(v, __shfl_xor(v, 16));
    return v;
}

// ---------------- all fp32 -> bf16 conversions in one kernel ----------------
#define NEC 4194304
#define WNC 262144
__global__ __launch_bounds__(256) void conv_all(
    const float* __restrict__ X, const float* __restrict__ Wq,
    const float* __restrict__ W1, const float* __restrict__ W2,
    ushort_t* __restrict__ Xb, ushort_t* __restrict__ Wb)
{
    int i = (blockIdx.x * 256 + threadIdx.x) * 4;
    const float* src; ushort_t* dst; int off, doff;
    if (i < NEC) { src = X; dst = Xb; off = i; doff = i; }
    else {
        int k = i - NEC;
        dst = Wb; doff = k;
        if (k < WNC)          { src = Wq; off = k; }
        else if (k < 2 * WNC) { src = W1; off = k - WNC; }
        else                  { src = W2; off = k - 2 * WNC; }
    }
    float4 v = *(const float4*)&src[off];
    ushort4 o;
    o.x = f2b(v.x); o.y = f2b(v.y); o.z = f2b(v.z); o.w = f2b(v.w);
    *(ushort4*)&dst[doff] = o;
}

// ---------------- bf16 MFMA GEMM, 128x64 tile, BK=64 ----------------
// C = act(A @ W^T + bias) [+ bf16 resid]. 4 waves (2x2), wave tile 64x32.
__device__ __forceinline__ void gload16(const void* g, void* l) {
    __builtin_amdgcn_global_load_lds(
        (const __attribute__((address_space(1))) unsigned*)g,
        (__attribute__((address_space(3))) unsigned*)l, 16, 0, 0);
}

template<int ACT, bool RES, bool OBF16>
__global__ __launch_bounds__(256) void gemm_mfma(
    const ushort_t* __restrict__ A, const ushort_t* __restrict__ W,
    const float* __restrict__ bias, const ushort_t* __restrict__ resid,
    void* __restrict__ Cout, int M, int N, int K)
{
    __shared__ ushort_t Asw[128 * 64];   // rows of 64 cols (128B = 8 granules)
    __shared__ ushort_t Bsw[64 * 64];

    const int tid = threadIdx.x;
    const int w = tid >> 6, lane = tid & 63;
    const int wm = w >> 1, wn = w & 1;
    const int bm = blockIdx.y * 128, bn = blockIdx.x * 64;

    const int l3 = lane >> 3, l7 = lane & 7;
    const int srcg = l7 ^ l3;               // pre-swizzled source granule
    const int l15 = lane & 15, hi = lane >> 4;

    f32x4 acc[4][2] = {};

    for (int kt = 0; kt < K; kt += 64) {
        #pragma unroll
        for (int u = 0; u < 4; ++u) {       // A: 16 row-groups of 8
            int q = w * 4 + u;
            gload16(&A[(size_t)(bm + q * 8 + l3) * K + kt + srcg * 8], &Asw[q * 512]);
        }
        #pragma unroll
        for (int u = 0; u < 2; ++u) {       // B: 8 row-groups of 8
            int q = w * 2 + u;
            gload16(&W[(size_t)(bn + q * 8 + l3) * K + kt + srcg * 8], &Bsw[q * 512]);
        }
        __syncthreads();

        #pragma unroll
        for (int kk = 0; kk < 2; ++kk) {
            const int s = (kk * 4 + hi) ^ l7;   // swizzled read granule (row&7 == l7)
            short8 a[4], b[2];
            #pragma unroll
            for (int f = 0; f < 4; ++f)
                a[f] = *(const short8*)&Asw[(wm * 64 + f * 16 + l15) * 64 + s * 8];
            #pragma unroll
            for (int f = 0; f < 2; ++f)
                b[f] = *(const short8*)&Bsw[(wn * 32 + f * 16 + l15) * 64 + s * 8];
            #pragma unroll
            for (int i = 0; i < 4; ++i)
                #pragma unroll
                for (int j = 0; j < 2; ++j)
                    acc[i][j] = __builtin_amdgcn_mfma_f32_16x16x32_bf16(
                        a[i], b[j], acc[i][j], 0, 0, 0);
        }
        __syncthreads();
    }

    #pragma unroll
    for (int i = 0; i < 4; ++i) {
        #pragma unroll
        for (int j = 0; j < 2; ++j) {
            #pragma unroll
            for (int r = 0; r < 4; ++r) {
                const int m = bm + wm * 64 + i * 16 + hi * 4 + r;
                const int n = bn + wn * 32 + j * 16 + l15;
                float v = acc[i][j][r] + bias[n];
                if (ACT == 1) v = fmaxf(v, 0.f);
                if (RES) v += b2f(resid[(size_t)m * N + n]);
                if (OBF16) ((ushort_t*)Cout)[(size_t)m * N + n] = f2b(v);
                else       ((float*)Cout)[(size_t)m * N + n] = v;
            }
        }
    }
}

// ---------------- Ktb[b,h][d][j] = Xb[b,j,h*64+d] (bf16) ----------------
__global__ __launch_bounds__(256) void transpose_kt(const ushort_t* __restrict__ Xb,
                                                    ushort_t* __restrict__ Ktb)
{
    int o = blockIdx.x * 256 + threadIdx.x;
    int j = o & 511;
    int d = (o >> 9) & 63;
    int h = (o >> 15) & 7;
    int b = o >> 18;
    Ktb[o] = Xb[((b << 9) + j) * 512 + h * 64 + d];
}

// ---------------- alpha per (b,h), bf16 q ----------------
__global__ void alpha_kernel(const ushort_t* __restrict__ Qb, const float* __restrict__ Wa,
                             const float* __restrict__ ba,
                             float* __restrict__ am1v, float* __restrict__ invv)
{
    int t = threadIdx.x;
    if (t >= BB * HH) return;
    int b = t >> 3, h = t & 7;
    float acc = 0.f;
    #pragma unroll
    for (int d = 0; d < HDIM; ++d)
        acc = fmaf(b2f(Qb[((b << 9) + 511) * 512 + h * 64 + d]), Wa[d], acc);
    acc += ba[0];
    float sig = 1.f / (1.f + expf(-acc));
    float alpha = sig + 1.f;
    const float amin = 1.f + 1e-5f;
    if (alpha < amin) alpha = amin;
    float am1 = alpha - 1.f;
    am1v[t] = am1;
    invv[t] = 1.f / am1;
}

// ---------------- fused attention v11 ----------------
#define SLS 520
__global__ __launch_bounds__(256, 4) void attn_kernel(
    const ushort_t* __restrict__ Qb, const ushort_t* __restrict__ Xb,
    const ushort_t* __restrict__ Ktb,
    const float* __restrict__ mask, const float* __restrict__ am1v,
    const float* __restrict__ invv, ushort_t* __restrict__ ATTb)
{
    __shared__ ushort_t qsb[16][72];   // bf16 Q rows
    __shared__ float SL[16][SLS];      // masked scaled scores -> bf16 P; [row][512]=1/S
    __shared__ float attbuf[16][68];   // mask[512] (phases A-C), att^T staging (D)

    const int bid = ((blockIdx.x & 7) << 9) + (blockIdx.x >> 3);   // XCD swizzle
    const int bh = bid >> 5;
    const int rg = bid & 31;
    const int b = bh >> 3, h = bh & 7;
    const int tid = threadIdx.x;
    const int w = tid >> 6, lane = tid & 63;
    const int l15 = lane & 15, hi = lane >> 4;

    const float am1 = am1v[bh];
    const float inv = invv[bh];
    const float im1c = fmaxf(inv - 1.f, 1e-30f);   // >0 so im1c*log2(0) = -inf -> 0
    const float NEG = -__builtin_inff();
    const float sc = 0.125f * am1;
    float* mlds = &attbuf[0][0];

    // ---- phase A: bf16 Q tile + mask -> LDS ----
    {
        int idx = tid * 4;
        int rr = idx >> 6, d4 = idx & 63;
        *(ushort4*)&qsb[rr][d4] =
            *(const ushort4*)&Qb[((size_t)((b << 9) + rg * 16 + rr)) * 512 + (h << 6) + d4];
    }
    #pragma unroll
    for (int u = 0; u < 2; ++u) {
        int j = tid + u * 256;
        mlds[j] = (j < 511) ? mask[b * 511 + j] : 0.f;   // last key always masked
    }
    __syncthreads();

    // ---- phase B: S^T = K·Q^T via MFMA; mask+scale applied at write ----
    {
        const ushort_t* xa = Xb + ((size_t)(b << 9)) * 512 + (h << 6);
        #pragma unroll
        for (int jt = 0; jt < 8; ++jt) {
            const int j0 = w * 128 + jt * 16;
            f32x4 acc = {0.f, 0.f, 0.f, 0.f};
            #pragma unroll
            for (int ks = 0; ks < 2; ++ks) {
                short8 a = *(const short8*)&xa[(size_t)(j0 + l15) * 512 + ks * 32 + hi * 8];
                short8 bf = *(const short8*)&qsb[l15][ks * 32 + hi * 8];
                acc = __builtin_amdgcn_mfma_f32_16x16x32_bf16(a, bf, acc, 0, 0, 0);
            }
            #pragma unroll
            for (int r = 0; r < 4; ++r) {
                int j = j0 + hi * 4 + r;
                float mv = mlds[j];                      // 16-lane broadcast
                SL[l15][j] = (mv == 0.f) ? NEG : acc[r] * sc;
            }
        }
    }
    __syncthreads();

    // ---- phase C: entmax Newton; 2 passes x (two 32-lane groups, 1 row each) ----
    const int l5 = lane & 31, gg = lane >> 5;
    ushort_t* SLu = (ushort_t*)&SL[0][0];        // row q at SLu + q*1040

    #pragma unroll
    for (int pp = 0; pp < 2; ++pp) {
        const int row = w * 4 + pp * 2 + gg;

        float Xs[16];
        #pragma unroll
        for (int u = 0; u < 8; ++u) {
            float2 sv = *(const float2*)&SL[row][u * 64 + 2 * l5];
            Xs[2*u] = sv.x; Xs[2*u+1] = sv.y;
        }

        float mx = Xs[0];
        #pragma unroll
        for (int e = 1; e < 16; ++e) mx = fmaxf(mx, Xs[e]);
        mx = rmax32(mx);

        float tau = mx - 1.f;      // f(tau) >= 0 here; f convex decreasing
        for (int it = 0; it < NNEWT; ++it) {
            float s0 = 0.f, s1 = 0.f, g0 = 0.f, g1 = 0.f;
            #pragma unroll
            for (int e = 0; e < 16; e += 2) {
                // z <= 1 provably (tau >= mx-1), so [0,1] clamp == max(z,0)
                float za = fminf(fmaxf(Xs[e]     - tau, 0.f), 1.f);
                float zb = fminf(fmaxf(Xs[e + 1] - tau, 0.f), 1.f);
                float da = hw_exp2(im1c * hw_log2(za));   // za^(inv-1); 0 at za=0
                float db = hw_exp2(im1c * hw_log2(zb));
                s0 += da * za; g0 += da;
                s1 += db * zb; g1 += db;
            }
            float S  = rsum32(s0 + s1);
            float Sp = rsum32(g0 + g1);
            tau += (S - 1.f) * hw_rcp(inv * Sp);   // approx step: fine, fixed iters
        }

        // final eval: unnormalized p -> bf16 packed u32; 1/S at fp32 [512]
        float s0 = 0.f, s1 = 0.f;
        #pragma unroll
        for (int u = 0; u < 8; ++u) {
            int j0 = u * 64 + 2 * l5;
            float za = fminf(fmaxf(Xs[2*u]   - tau, 0.f), 1.f);
            float zb = fminf(fmaxf(Xs[2*u+1] - tau, 0.f), 1.f);
            float pa = hw_exp2(inv * hw_log2(za));       // inv>=1: exp2(-inf)=0
            float pb = hw_exp2(inv * hw_log2(zb));
            unsigned pk = (unsigned)f2b(pa) | ((unsigned)f2b(pb) << 16);
            *(unsigned*)&SLu[row * 1040 + j0] = pk;
            s0 += pa; s1 += pb;
        }
        float S = rsum32(s0 + s1);
        if (l5 == 0) SL[row][512] = 1.f / S;
    }
    __syncthreads();   // also separates mask use (attbuf) from phase D writes

    // ---- phase D: att^T = X^T·P^T via MFMA; wave w owns d-tile [w*16,w*16+16) ----
    {
        const ushort_t* ka = Ktb + (size_t)bh * (64 * 512) + (size_t)(w * 16 + l15) * 512;
        const ushort_t* pb = SLu + l15 * 1040;
        f32x4 acc0 = {0.f, 0.f, 0.f, 0.f};
        f32x4 acc1 = {0.f, 0.f, 0.f, 0.f};
        #pragma unroll
        for (int ks = 0; ks < 16; ks += 2) {
            short8 a0 = *(const short8*)&ka[ks * 32 + hi * 8];
            short8 b0 = *(const short8*)&pb[ks * 32 + hi * 8];
            short8 a1 = *(const short8*)&ka[(ks + 1) * 32 + hi * 8];
            short8 b1 = *(const short8*)&pb[(ks + 1) * 32 + hi * 8];
            acc0 = __builtin_amdgcn_mfma_f32_16x16x32_bf16(a0, b0, acc0, 0, 0, 0);
            acc1 = __builtin_amdgcn_mfma_f32_16x16x32_bf16(a1, b1, acc1, 0, 0, 0);
        }
        #pragma unroll
        for (int r = 0; r < 4; ++r)
            attbuf[l15][w * 16 + hi * 4 + r] = acc0[r] + acc1[r];
    }
    __syncthreads();

    // ---- store: normalize, write bf16 ATTb coalesced (ushort4 = 8B/lane) ----
    {
        int idx = tid * 4;
        int q = idx >> 6, d4 = idx & 63;
        float rn = SL[q][512];
        ushort4 o;
        o.x = f2b(attbuf[q][d4 + 0] * rn);
        o.y = f2b(attbuf[q][d4 + 1] * rn);
        o.z = f2b(attbuf[q][d4 + 2] * rn);
        o.w = f2b(attbuf[q][d4 + 3] * rn);
        *(ushort4*)&ATTb[((size_t)((b << 9) + rg * 16 + q)) * 512 + (h << 6) + d4] = o;
    }
}

// ---------------- LayerNorm + scatter ----------------
__global__ __launch_bounds__(256) void ln_kernel(const float* __restrict__ Cb,
                                                 const float* __restrict__ g,
                                                 const float* __restrict__ beta,
                                                 float* __restrict__ out)
{
    const int w = threadIdx.x >> 6, lane = threadIdx.x & 63;
    const int row = blockIdx.x * 4 + w;
    const int b = row >> 9, l = row & 511;
    const float* x = Cb + (size_t)row * 512;

    float v[8], s = 0.f;
    #pragma unroll
    for (int k = 0; k < 8; ++k) { v[k] = x[k * 64 + lane]; s += v[k]; }
    s = wsum(s);
    float mu = s * (1.f / 512.f);
    float q = 0.f;
    #pragma unroll
    for (int k = 0; k < 8; ++k) { float d = v[k] - mu; q = fmaf(d, d, q); }
    q = wsum(q);
    float rs = rsqrtf(q * (1.f / 512.f) + 1e-12f);

    float* dst = (l < 511) ? (out + (size_t)(b * 511 + l) * 512)
                           : (out + (size_t)16 * 511 * 512 + (size_t)b * 512);
    #pragma unroll
    for (int k = 0; k < 8; ++k) {
        int d = k * 64 + lane;
        dst[d] = (v[k] - mu) * rs * g[d] + beta[d];
    }
}

// ---------------- launch ----------------
extern "C" void kernel_launch(void* const* d_in, const int* in_sizes, int n_in,
                              void* d_out, int out_size, void* d_ws, size_t ws_size,
                              hipStream_t stream)
{
    const float* X    = (const float*)d_in[0];
    const float* mask = (const float*)d_in[1];
    const float* Wq   = (const float*)d_in[2];
    const float* bq   = (const float*)d_in[3];
    const float* W1   = (const float*)d_in[4];
    const float* b1   = (const float*)d_in[5];
    const float* W2   = (const float*)d_in[6];
    const float* b2   = (const float*)d_in[7];
    const float* lng  = (const float*)d_in[8];
    const float* lnb  = (const float*)d_in[9];
    const float* Wa   = (const float*)d_in[10];
    const float* ba   = (const float*)d_in[11];
    float* out = (float*)d_out;
    float* ws  = (float*)d_ws;

    const size_t NE = (size_t)BB * LL * DD;      // 4194304
    const size_t WN = (size_t)DD * DD;           // 262144
    if (ws_size < (3 * NE + 256) * sizeof(float) + 3 * WN * sizeof(ushort_t)) return;

    float* am1v = ws + 3 * NE;
    float* invv = am1v + 128;
    ushort_t* Wqb = (ushort_t*)(am1v + 256);
    ushort_t* W1b = Wqb + WN;
    ushort_t* W2b = W1b + WN;
    ushort_t* Qbb = (ushort_t*)ws;
    ushort_t* Hhb = Qbb + NE;
    ushort_t* ATTb = (ushort_t*)(ws + NE);
    ushort_t* Xb  = (ushort_t*)(ws + 2 * NE);
    ushort_t* Ktb = Xb + NE;
    float* Cb = ws + 2 * NE;               // Xb/Ktb dead after attn

    const int M = BB * LL;       // 8192

    conv_all<<<(int)((NE + 3 * WN) / 1024), 256, 0, stream>>>(X, Wq, W1, W2, Xb, Wqb);
    gemm_mfma<1, false, true><<<dim3(DD / 64, M / 128), 256, 0, stream>>>(
        Xb, Wqb, bq, nullptr, Qbb, M, DD, DD);
    transpose_kt<<<(int)(NE / 256), 256, 0, stream>>>(Xb, Ktb);
    alpha_kernel<<<1, 128, 0, stream>>>(Qbb, Wa, ba, am1v, invv);
    attn_kernel<<<BB * HH * LL / 16, 256, 0, stream>>>(Qbb, Xb, Ktb, mask, am1v, invv, ATTb);
    gemm_mfma<1, false, true><<<dim3(DD / 64, M / 128), 256, 0, stream>>>(
        ATTb, W1b, b1, nullptr, Hhb, M, DD, DD);
    gemm_mfma<0, true, false><<<dim3(DD / 64, M / 128), 256, 0, stream>>>(
        Hhb, W2b, b2, ATTb, Cb, M, DD, DD);
    ln_kernel<<<M / 4, 256, 0, stream>>>(Cb, lng, lnb, out);
}